// Round 1
// baseline (298.538 us; speedup 1.0000x reference)
//
#include <hip/hip_runtime.h>

#define NN 4096
#define HEADS 8
#define DD 64
#define QKD 512
#define QBLK 64
#define KBLK 64
#define THREADS 512

typedef __attribute__((ext_vector_type(8))) short short8;
typedef __attribute__((ext_vector_type(4))) float f32x4;
typedef __attribute__((ext_vector_type(4))) float float4v;
typedef __attribute__((ext_vector_type(4))) int int4v;
typedef unsigned int u32;
typedef unsigned short u16;

union U8 { u16 u[8]; short8 s; };
union U4 { u32 u[4]; short8 s; };

__device__ __forceinline__ u16 f2bf(float f) {
  u32 u = __float_as_uint(f);
  u += 0x7fffu + ((u >> 16) & 1u);   // RNE
  return (u16)(u >> 16);
}

// ---------- preprocess: bf16 copies of x2 (K) and v (V) into workspace ----------
__global__ __launch_bounds__(256) void cvt_kernel(const float* __restrict__ x2,
                                                  const float* __restrict__ v,
                                                  u16* __restrict__ Kb,
                                                  u16* __restrict__ Vb) {
  const int ELEMS = NN * QKD;  // 2M per matrix
  int base = (blockIdx.x * 256 + threadIdx.x) * 8;
  const float* src; u16* dst; int off;
  if (base < ELEMS) { src = x2; dst = Kb; off = base; }
  else              { src = v;  dst = Vb; off = base - ELEMS; }
  float4v a = *(const float4v*)(src + off);
  float4v b = *(const float4v*)(src + off + 4);
  U8 r;
  r.u[0] = f2bf(a.x); r.u[1] = f2bf(a.y); r.u[2] = f2bf(a.z); r.u[3] = f2bf(a.w);
  r.u[4] = f2bf(b.x); r.u[5] = f2bf(b.y); r.u[6] = f2bf(b.z); r.u[7] = f2bf(b.w);
  *(short8*)(dst + off) = r.s;
}

// ---------- fused masked attention ----------
// Block: Q-tile of 64 rows x 2 heads. 8 waves: wave w -> head h0+(w&1), q-rows qsub=w>>1.
// Per K-tile (64): swapped QK^T (lane owns its q-row's scores), exp2 online softmax,
// P redistributed via bpermute to B-frag layout, swapped PV (out^T in C-layout).
template <bool USE_BF16>
__global__ __launch_bounds__(THREADS) void attn_kernel(
    const float* __restrict__ x1, const float* __restrict__ x2f,
    const float* __restrict__ vf, const int* __restrict__ adj,
    const u16* __restrict__ Kb, const u16* __restrict__ Vb,
    float* __restrict__ out)
{
  __shared__ u16 Klds[64 * 128];                // [k][c(2 heads)] bf16, XOR-swizzled
  __shared__ u16 Vlds[128 * 64];                // [vd(2 heads)][k] bf16 transposed, swizzled
  __shared__ unsigned long long Abits[64];      // adj bitmask [q_local] bit=k_local

  const int b = blockIdx.x;
  const int qt = (b & 7) | ((b >> 5) << 3);     // XCD swizzle: 4 head-groups of a qtile share an XCD
  const int hg = (b >> 3) & 3;
  const int h0 = hg * 2;
  const int t = threadIdx.x;
  const int w = t >> 6;
  const int lane = t & 63;
  const int qsub = w >> 1;
  const int hh = w & 1;
  const int h = h0 + hh;
  const int g = lane >> 4;
  const int qi = lane & 15;
  const int qbase = qt * QBLK;
  const int q_local = qsub * 16 + qi;
  const int qrow = qbase + q_local;

  // Q fragments (B operand of S^T mfma): Q[qrow][h*64 + dc*32 + g*8 + e], pre-scaled
  const float SCL = 0.125f * 1.4426950408889634f;  // SCALE * log2(e) -> exp2 softmax
  short8 qfrag[2];
  #pragma unroll
  for (int dc = 0; dc < 2; dc++) {
    const float* p = x1 + (size_t)qrow * QKD + h * DD + dc * 32 + g * 8;
    float4v a = *(const float4v*)p;
    float4v c = *(const float4v*)(p + 4);
    U8 r;
    r.u[0] = f2bf(a.x * SCL); r.u[1] = f2bf(a.y * SCL);
    r.u[2] = f2bf(a.z * SCL); r.u[3] = f2bf(a.w * SCL);
    r.u[4] = f2bf(c.x * SCL); r.u[5] = f2bf(c.y * SCL);
    r.u[6] = f2bf(c.z * SCL); r.u[7] = f2bf(c.w * SCL);
    qfrag[dc] = r.s;
  }

  const f32x4 zero = {0.f, 0.f, 0.f, 0.f};
  f32x4 Ot[4] = {zero, zero, zero, zero};       // out^T accum, col = own q
  float mrun = -1e30f;
  float lsum = 0.f;

  for (int kb = 0; kb < NN / KBLK; kb++) {
    const int k0 = kb * KBLK;
    __syncthreads();
    // ---- stage K tile: Klds[k 0..63][c 0..127]
    #pragma unroll
    for (int i = 0; i < 2; i++) {
      int s = t + i * THREADS;
      int row = s >> 4, c0 = (s & 15) * 8;
      int off = (row * 256 + c0 * 2) ^ ((row & 7) << 4);
      if (USE_BF16) {
        short8 val = *(const short8*)(Kb + (size_t)(k0 + row) * QKD + h0 * DD + c0);
        *(short8*)((char*)Klds + off) = val;
      } else {
        const float* p = x2f + (size_t)(k0 + row) * QKD + h0 * DD + c0;
        float4v a = *(const float4v*)p;
        float4v c = *(const float4v*)(p + 4);
        U8 r;
        r.u[0]=f2bf(a.x); r.u[1]=f2bf(a.y); r.u[2]=f2bf(a.z); r.u[3]=f2bf(a.w);
        r.u[4]=f2bf(c.x); r.u[5]=f2bf(c.y); r.u[6]=f2bf(c.z); r.u[7]=f2bf(c.w);
        *(short8*)((char*)Klds + off) = r.s;
      }
    }
    // ---- stage V tile TRANSPOSED: Vlds[vd][k], pack (k, k+1) pairs as u32
    {
      int vdg = t & 15, kp = t >> 4;
      int vd0 = vdg * 8, kk = kp * 2;
      u16 ua[8], ub[8];
      if (USE_BF16) {
        const u16* pa = Vb + (size_t)(k0 + kk) * QKD + h0 * DD + vd0;
        short8 va = *(const short8*)pa;
        short8 vb2 = *(const short8*)(pa + QKD);
        #pragma unroll
        for (int j = 0; j < 8; j++) { ua[j] = (u16)va[j]; ub[j] = (u16)vb2[j]; }
      } else {
        const float* pa = vf + (size_t)(k0 + kk) * QKD + h0 * DD + vd0;
        float4v a0 = *(const float4v*)pa;
        float4v a1 = *(const float4v*)(pa + 4);
        float4v b0 = *(const float4v*)(pa + QKD);
        float4v b1 = *(const float4v*)(pa + QKD + 4);
        ua[0]=f2bf(a0.x); ua[1]=f2bf(a0.y); ua[2]=f2bf(a0.z); ua[3]=f2bf(a0.w);
        ua[4]=f2bf(a1.x); ua[5]=f2bf(a1.y); ua[6]=f2bf(a1.z); ua[7]=f2bf(a1.w);
        ub[0]=f2bf(b0.x); ub[1]=f2bf(b0.y); ub[2]=f2bf(b0.z); ub[3]=f2bf(b0.w);
        ub[4]=f2bf(b1.x); ub[5]=f2bf(b1.y); ub[6]=f2bf(b1.z); ub[7]=f2bf(b1.w);
      }
      #pragma unroll
      for (int j = 0; j < 8; j++) {
        u32 pk2 = (u32)ua[j] | ((u32)ub[j] << 16);
        int vd = vd0 + j;
        int off = (vd * 128 + kk * 2) ^ (((vd & 7) ^ ((vd >> 3) & 7)) << 4);
        *(u32*)((char*)Vlds + off) = pk2;
      }
    }
    // ---- stage adj bitmask (shared by both heads)
    {
      int row = t >> 3, c8 = t & 7;
      const int* ap = adj + (size_t)(qbase + row) * NN + k0 + c8 * 8;
      int4v a0 = *(const int4v*)ap;
      int4v a1 = *(const int4v*)(ap + 4);
      u32 byteval = (u32)(a0.x > 0)        | ((u32)(a0.y > 0) << 1) |
                    ((u32)(a0.z > 0) << 2) | ((u32)(a0.w > 0) << 3) |
                    ((u32)(a1.x > 0) << 4) | ((u32)(a1.y > 0) << 5) |
                    ((u32)(a1.z > 0) << 6) | ((u32)(a1.w > 0) << 7);
      ((unsigned char*)Abits)[row * 8 + c8] = (unsigned char)byteval;
    }
    __syncthreads();

    // ---- S^T = K_tile . Q^T : lane holds S[q=qi][k = tk*16 + g*4 + r]
    f32x4 st[4] = {zero, zero, zero, zero};
    #pragma unroll
    for (int tk = 0; tk < 4; tk++) {
      #pragma unroll
      for (int dc = 0; dc < 2; dc++) {
        int krow = tk * 16 + qi;
        int c = hh * 64 + dc * 32 + g * 8;
        int off = (krow * 256 + c * 2) ^ ((krow & 7) << 4);
        short8 af = *(const short8*)((char*)Klds + off);
        st[tk] = __builtin_amdgcn_mfma_f32_16x16x32_bf16(af, qfrag[dc], st[tk], 0, 0, 0);
      }
    }

    unsigned long long bbm = Abits[q_local];
    u32 blo = (u32)bbm, bhi = (u32)(bbm >> 32);

    // ---- mask + online softmax (exp2 domain); -9e15 fill reproduces ref semantics
    float tmax = -1e30f;
    #pragma unroll
    for (int tk = 0; tk < 4; tk++) {
      u32 half = (tk < 2) ? blo : bhi;
      int bb0 = (tk & 1) * 16 + g * 4;
      #pragma unroll
      for (int r = 0; r < 4; r++) {
        float s = st[tk][r];
        s = ((half >> (bb0 + r)) & 1u) ? s : -9e15f;
        st[tk][r] = s;
        tmax = fmaxf(tmax, s);
      }
    }
    tmax = fmaxf(tmax, __shfl_xor(tmax, 16));
    tmax = fmaxf(tmax, __shfl_xor(tmax, 32));
    float newm = fmaxf(mrun, tmax);
    float alpha = __builtin_amdgcn_exp2f(mrun - newm);
    mrun = newm;

    float psum = 0.f;
    u32 pk[8];  // pk[tk*2+rp] = bf16 pair P(k=tk*16+g*4+2rp, +1)
    #pragma unroll
    for (int tk = 0; tk < 4; tk++) {
      float p0 = __builtin_amdgcn_exp2f(st[tk][0] - newm);
      float p1 = __builtin_amdgcn_exp2f(st[tk][1] - newm);
      float p2 = __builtin_amdgcn_exp2f(st[tk][2] - newm);
      float p3 = __builtin_amdgcn_exp2f(st[tk][3] - newm);
      psum += (p0 + p1) + (p2 + p3);
      pk[tk * 2 + 0] = (u32)f2bf(p0) | ((u32)f2bf(p1) << 16);
      pk[tk * 2 + 1] = (u32)f2bf(p2) | ((u32)f2bf(p3) << 16);
    }
    psum += __shfl_xor(psum, 16);
    psum += __shfl_xor(psum, 32);
    lsum = lsum * alpha + psum;
    #pragma unroll
    for (int tv = 0; tv < 4; tv++) {
      Ot[tv][0] *= alpha; Ot[tv][1] *= alpha; Ot[tv][2] *= alpha; Ot[tv][3] *= alpha;
    }

    // ---- redistribute P to B-frag layout (lane needs P[q=qi][k=kc*32+g*8+e]) + PV
    const int srcbase = qi + ((g & 1) << 5);
    #pragma unroll
    for (int kc = 0; kc < 2; kc++) {
      U4 pf;
      #pragma unroll
      for (int jp = 0; jp < 4; jp++) {
        int src = srcbase + ((jp >> 1) << 4);
        u32 va1 = (u32)__shfl((int)pk[4 * kc + (jp & 1)], src);
        u32 vb1 = (u32)__shfl((int)pk[4 * kc + 2 + (jp & 1)], src);
        pf.u[jp] = (g < 2) ? va1 : vb1;
      }
      #pragma unroll
      for (int tv = 0; tv < 4; tv++) {
        int vd = hh * 64 + tv * 16 + qi;
        int off = (vd * 128 + (kc * 32 + g * 8) * 2) ^ (((vd & 7) ^ ((vd >> 3) & 7)) << 4);
        short8 vfrag = *(const short8*)((char*)Vlds + off);
        Ot[tv] = __builtin_amdgcn_mfma_f32_16x16x32_bf16(vfrag, pf.s, Ot[tv], 0, 0, 0);
      }
    }
  }

  // ---- epilogue: out[qrow][h*64 + tv*16 + g*4 + r] = Ot / lsum
  float inv = 1.0f / lsum;
  #pragma unroll
  for (int tv = 0; tv < 4; tv++) {
    float4v o;
    o.x = Ot[tv][0] * inv; o.y = Ot[tv][1] * inv;
    o.z = Ot[tv][2] * inv; o.w = Ot[tv][3] * inv;
    *(float4v*)(out + (size_t)qrow * QKD + h * DD + tv * 16 + g * 4) = o;
  }
}

extern "C" void kernel_launch(void* const* d_in, const int* in_sizes, int n_in,
                              void* d_out, int out_size, void* d_ws, size_t ws_size,
                              hipStream_t stream) {
  const float* x1 = (const float*)d_in[0];
  const float* x2 = (const float*)d_in[1];
  const float* v  = (const float*)d_in[2];
  const int* adj  = (const int*)d_in[3];
  float* out = (float*)d_out;

  const size_t need = (size_t)2 * NN * QKD * sizeof(u16);  // 8 MB
  const bool use_bf16 = (ws_size >= need) && (d_ws != nullptr);
  u16* Kb = (u16*)d_ws;
  u16* Vb = Kb + (size_t)NN * QKD;

  if (use_bf16) {
    cvt_kernel<<<dim3(2048), dim3(256), 0, stream>>>(x2, v, Kb, Vb);
    attn_kernel<true><<<dim3(256), dim3(THREADS), 0, stream>>>(x1, x2, v, adj, Kb, Vb, out);
  } else {
    attn_kernel<false><<<dim3(256), dim3(THREADS), 0, stream>>>(x1, x2, v, adj, Kb, Vb, out);
  }
}

// Round 2
// 228.795 us; speedup vs baseline: 1.3048x; 1.3048x over previous
//
#include <hip/hip_runtime.h>

#define NN 4096
#define HEADS 8
#define DD 64
#define QKD 512

typedef __attribute__((ext_vector_type(8))) short short8;
typedef __attribute__((ext_vector_type(4))) float f32x4;
typedef __attribute__((ext_vector_type(4))) float float4v;
typedef __attribute__((ext_vector_type(4))) int int4v;
typedef unsigned int u32;
typedef unsigned short u16;
typedef unsigned long long u64;

union U8 { u16 u[8]; short8 s; };
union U4 { u32 u[4]; short8 s; };

__device__ __forceinline__ u16 f2bf(float f) {
  u32 u = __float_as_uint(f);
  u += 0x7fffu + ((u >> 16) & 1u);   // RNE
  return (u16)(u >> 16);
}

// ============================================================================
// Prepass 1: adjacency -> bitmask.  Abg[row*64 + kb] bit j = (adj[row][kb*64+j] > 0)
// 64 MB int32 read once, 2 MB u64 written. One block per row; ballot packs 64 lanes.
// ============================================================================
__global__ __launch_bounds__(256) void pack_adj(const int* __restrict__ adj,
                                                u64* __restrict__ Abg) {
  const int row = blockIdx.x;
  const int w = threadIdx.x >> 6, lane = threadIdx.x & 63;
  const int* base = adj + (size_t)row * NN;
  #pragma unroll
  for (int i = 0; i < 16; i++) {
    int idx = w * 16 + i;
    int val = base[idx * 64 + lane];
    u64 m = __ballot(val > 0);
    if (lane == 0) Abg[(size_t)row * 64 + idx] = m;
  }
}

// ============================================================================
// Prepass 2: K and V -> bf16 tiles in the exact (swizzled) LDS image layout.
// K tile (h,kb), 8 KB:  I[off] = K[kb*64+kr][h*64+d],  off = kr*128 + d*2 ^ ((kr&7)<<4)
// V tile (h,kb), 8 KB:  I[off] = V[kb*64+k ][h*64+vd], off = vd*128 + k*2 ^ ((vd&7)<<4)
// (V transposed via LDS so both global read and global write stay coalesced)
// ============================================================================
__global__ __launch_bounds__(256) void cvt_kv(const float* __restrict__ x2,
                                              const float* __restrict__ v,
                                              u16* __restrict__ Kbt,
                                              u16* __restrict__ Vbt) {
  __shared__ u16 Vtmp[64][80];   // pad 80 -> 160B rows (16B aligned)
  const int b = blockIdx.x;
  const int t = threadIdx.x;
  if (b < 512) {                       // ---- K tiles
    const int h = b >> 6, kb = b & 63;
    u16* dst = Kbt + (size_t)b * 4096;
    #pragma unroll
    for (int i = 0; i < 2; i++) {
      int c = t + i * 256;
      int off = c * 16;
      int kr = off >> 7;
      int db = (off & 127) ^ ((kr & 7) << 4);
      int d0 = db >> 1;
      const float* p = x2 + (size_t)(kb * 64 + kr) * QKD + h * DD + d0;
      float4v a0 = *(const float4v*)p;
      float4v a1 = *(const float4v*)(p + 4);
      U8 r;
      r.u[0] = f2bf(a0.x); r.u[1] = f2bf(a0.y); r.u[2] = f2bf(a0.z); r.u[3] = f2bf(a0.w);
      r.u[4] = f2bf(a1.x); r.u[5] = f2bf(a1.y); r.u[6] = f2bf(a1.z); r.u[7] = f2bf(a1.w);
      *(short8*)((char*)dst + off) = r.s;
    }
  } else {                             // ---- V tiles (transpose)
    const int bb = b - 512;
    const int h = bb >> 6, kb = bb & 63;
    {
      int k = t >> 2, j0 = (t & 3) * 16;
      const float* p = v + (size_t)(kb * 64 + k) * QKD + h * DD + j0;
      float4v a0 = *(const float4v*)p;
      float4v a1 = *(const float4v*)(p + 4);
      float4v a2 = *(const float4v*)(p + 8);
      float4v a3 = *(const float4v*)(p + 12);
      U8 r0, r1;
      r0.u[0] = f2bf(a0.x); r0.u[1] = f2bf(a0.y); r0.u[2] = f2bf(a0.z); r0.u[3] = f2bf(a0.w);
      r0.u[4] = f2bf(a1.x); r0.u[5] = f2bf(a1.y); r0.u[6] = f2bf(a1.z); r0.u[7] = f2bf(a1.w);
      r1.u[0] = f2bf(a2.x); r1.u[1] = f2bf(a2.y); r1.u[2] = f2bf(a2.z); r1.u[3] = f2bf(a2.w);
      r1.u[4] = f2bf(a3.x); r1.u[5] = f2bf(a3.y); r1.u[6] = f2bf(a3.z); r1.u[7] = f2bf(a3.w);
      *(short8*)(&Vtmp[k][j0]) = r0.s;
      *(short8*)(&Vtmp[k][j0 + 8]) = r1.s;
    }
    __syncthreads();
    u16* dst = Vbt + (size_t)bb * 4096;
    #pragma unroll
    for (int i = 0; i < 2; i++) {
      int c = t + i * 256;
      int off = c * 16;
      int vd = off >> 7;
      int kbyte = (off & 127) ^ ((vd & 7) << 4);
      int k0 = kbyte >> 1;
      U8 r;
      #pragma unroll
      for (int j = 0; j < 8; j++) r.u[j] = Vtmp[k0 + j][vd];
      *(short8*)((char*)dst + off) = r.s;
    }
  }
}

// ============================================================================
// Main fused kernel. Grid 512 (64 q-tiles x 8 heads), 256 threads (4 waves).
// Wave w owns q-rows qt*64 + w*16 + qi. Double-buffered LDS, global_load_lds
// staging from pre-swizzled tiles, one barrier per K-tile.
// ============================================================================
__global__ __launch_bounds__(256) void attn_fast(
    const float* __restrict__ x1,
    const u64* __restrict__ Abg,
    const u16* __restrict__ Kbt, const u16* __restrict__ Vbt,
    float* __restrict__ out)
{
  __shared__ u16 Klds[2][4096];
  __shared__ u16 Vlds[2][4096];

  const int b = blockIdx.x;
  const int widx = ((b & 7) << 6) | (b >> 3);   // XCD-chunked: XCD x gets works x*64..x*64+63
  const int qt = widx >> 3;
  const int h = widx & 7;
  const int t = threadIdx.x;
  const int w = t >> 6;
  const int lane = t & 63;
  const int g = lane >> 4;
  const int qi = lane & 15;
  const int qrow = qt * 64 + w * 16 + qi;

  const u16* Ktiles = Kbt + (size_t)h * 64 * 4096;
  const u16* Vtiles = Vbt + (size_t)h * 64 * 4096;
  const u64* arow = Abg + (size_t)qrow * 64;

  // Q fragment (B operand): Q[qrow][h*64 + dc*32 + g*8 + e], pre-scaled into exp2 domain
  const float SCL = 0.125f * 1.4426950408889634f;
  short8 qfrag[2];
  #pragma unroll
  for (int dc = 0; dc < 2; dc++) {
    const float* p = x1 + (size_t)qrow * QKD + h * DD + dc * 32 + g * 8;
    float4v a = *(const float4v*)p;
    float4v c = *(const float4v*)(p + 4);
    U8 r;
    r.u[0] = f2bf(a.x * SCL); r.u[1] = f2bf(a.y * SCL);
    r.u[2] = f2bf(a.z * SCL); r.u[3] = f2bf(a.w * SCL);
    r.u[4] = f2bf(c.x * SCL); r.u[5] = f2bf(c.y * SCL);
    r.u[6] = f2bf(c.z * SCL); r.u[7] = f2bf(c.w * SCL);
    qfrag[dc] = r.s;
  }

  const f32x4 zero = {0.f, 0.f, 0.f, 0.f};
  f32x4 Ot[4] = {zero, zero, zero, zero};
  float mrun = -1e30f;
  float lsum = 0.f;

  // stage tile 0 into buffer 0
  {
    const u16* sk = Ktiles + t * 8;
    const u16* sv = Vtiles + t * 8;
    u16* dk = &Klds[0][t * 8];
    u16* dv = &Vlds[0][t * 8];
    __builtin_amdgcn_global_load_lds((const __attribute__((address_space(1))) void*)sk,
                                     (__attribute__((address_space(3))) void*)dk, 16, 0, 0);
    __builtin_amdgcn_global_load_lds((const __attribute__((address_space(1))) void*)(sk + 2048),
                                     (__attribute__((address_space(3))) void*)(dk + 2048), 16, 0, 0);
    __builtin_amdgcn_global_load_lds((const __attribute__((address_space(1))) void*)sv,
                                     (__attribute__((address_space(3))) void*)dv, 16, 0, 0);
    __builtin_amdgcn_global_load_lds((const __attribute__((address_space(1))) void*)(sv + 2048),
                                     (__attribute__((address_space(3))) void*)(dv + 2048), 16, 0, 0);
  }
  u64 adjcur = arow[0];
  __syncthreads();

  int cur = 0;
  for (int kb = 0; kb < NN / 64; kb++) {
    // ---- issue next-tile staging (flies during compute, drained at the barrier)
    u64 adjnext = 0;
    if (kb < NN / 64 - 1) {
      const u16* sk = Ktiles + (size_t)(kb + 1) * 4096 + t * 8;
      const u16* sv = Vtiles + (size_t)(kb + 1) * 4096 + t * 8;
      u16* dk = &Klds[cur ^ 1][t * 8];
      u16* dv = &Vlds[cur ^ 1][t * 8];
      __builtin_amdgcn_global_load_lds((const __attribute__((address_space(1))) void*)sk,
                                       (__attribute__((address_space(3))) void*)dk, 16, 0, 0);
      __builtin_amdgcn_global_load_lds((const __attribute__((address_space(1))) void*)(sk + 2048),
                                       (__attribute__((address_space(3))) void*)(dk + 2048), 16, 0, 0);
      __builtin_amdgcn_global_load_lds((const __attribute__((address_space(1))) void*)sv,
                                       (__attribute__((address_space(3))) void*)dv, 16, 0, 0);
      __builtin_amdgcn_global_load_lds((const __attribute__((address_space(1))) void*)(sv + 2048),
                                       (__attribute__((address_space(3))) void*)(dv + 2048), 16, 0, 0);
      adjnext = arow[kb + 1];
    }

    // ---- S^T = K_tile . Q^T : lane holds S[q=qi][k = tk*16 + g*4 + r]
    const char* kbase = (const char*)Klds[cur];
    f32x4 st[4] = {zero, zero, zero, zero};
    #pragma unroll
    for (int tk = 0; tk < 4; tk++) {
      int krow = tk * 16 + qi;
      #pragma unroll
      for (int dc = 0; dc < 2; dc++) {
        int off = (krow * 128 + (dc * 32 + g * 8) * 2) ^ ((krow & 7) << 4);
        short8 af = *(const short8*)(kbase + off);
        st[tk] = __builtin_amdgcn_mfma_f32_16x16x32_bf16(af, qfrag[dc], st[tk], 0, 0, 0);
      }
    }

    u32 blo = (u32)adjcur, bhi = (u32)(adjcur >> 32);

    // ---- mask + online softmax (exp2 domain)
    float tmax = -1e30f;
    #pragma unroll
    for (int tk = 0; tk < 4; tk++) {
      u32 half = (tk < 2) ? blo : bhi;
      int bb0 = (tk & 1) * 16 + g * 4;
      #pragma unroll
      for (int r = 0; r < 4; r++) {
        float s = st[tk][r];
        s = ((half >> (bb0 + r)) & 1u) ? s : -9e15f;
        st[tk][r] = s;
        tmax = fmaxf(tmax, s);
      }
    }
    tmax = fmaxf(tmax, __shfl_xor(tmax, 16));
    tmax = fmaxf(tmax, __shfl_xor(tmax, 32));
    float newm = fmaxf(mrun, tmax);
    float alpha = __builtin_amdgcn_exp2f(mrun - newm);
    mrun = newm;

    float psum = 0.f;
    u32 pk[8];
    #pragma unroll
    for (int tk = 0; tk < 4; tk++) {
      float p0 = __builtin_amdgcn_exp2f(st[tk][0] - newm);
      float p1 = __builtin_amdgcn_exp2f(st[tk][1] - newm);
      float p2 = __builtin_amdgcn_exp2f(st[tk][2] - newm);
      float p3 = __builtin_amdgcn_exp2f(st[tk][3] - newm);
      psum += (p0 + p1) + (p2 + p3);
      pk[tk * 2 + 0] = (u32)f2bf(p0) | ((u32)f2bf(p1) << 16);
      pk[tk * 2 + 1] = (u32)f2bf(p2) | ((u32)f2bf(p3) << 16);
    }
    psum += __shfl_xor(psum, 16);
    psum += __shfl_xor(psum, 32);
    lsum = lsum * alpha + psum;
    #pragma unroll
    for (int tv = 0; tv < 4; tv++) {
      Ot[tv][0] *= alpha; Ot[tv][1] *= alpha; Ot[tv][2] *= alpha; Ot[tv][3] *= alpha;
    }

    // ---- redistribute P to B-frag layout + PV (out^T accumulation)
    const char* vbase = (const char*)Vlds[cur];
    const int srcbase = qi + ((g & 1) << 5);
    #pragma unroll
    for (int kc = 0; kc < 2; kc++) {
      U4 pf;
      #pragma unroll
      for (int jp = 0; jp < 4; jp++) {
        int src = srcbase + ((jp >> 1) << 4);
        u32 va1 = (u32)__shfl((int)pk[4 * kc + (jp & 1)], src);
        u32 vb1 = (u32)__shfl((int)pk[4 * kc + 2 + (jp & 1)], src);
        pf.u[jp] = (g < 2) ? va1 : vb1;
      }
      #pragma unroll
      for (int tv = 0; tv < 4; tv++) {
        int vd = tv * 16 + qi;
        int off = (vd * 128 + (kc * 32 + g * 8) * 2) ^ ((vd & 7) << 4);
        short8 vfrag = *(const short8*)(vbase + off);
        Ot[tv] = __builtin_amdgcn_mfma_f32_16x16x32_bf16(vfrag, pf.s, Ot[tv], 0, 0, 0);
      }
    }

    __syncthreads();   // drains the in-flight global_load_lds + barrier
    adjcur = adjnext;
    cur ^= 1;
  }

  // ---- epilogue
  float inv = 1.0f / lsum;
  #pragma unroll
  for (int tv = 0; tv < 4; tv++) {
    float4v o;
    o.x = Ot[tv][0] * inv; o.y = Ot[tv][1] * inv;
    o.z = Ot[tv][2] * inv; o.w = Ot[tv][3] * inv;
    *(float4v*)(out + (size_t)qrow * QKD + h * DD + tv * 16 + g * 4) = o;
  }
}

// ============================================================================
// Fallback (no workspace): round-1 kernel, f32 inputs converted in-kernel.
// ============================================================================
__global__ __launch_bounds__(512) void attn_fallback(
    const float* __restrict__ x1, const float* __restrict__ x2f,
    const float* __restrict__ vf, const int* __restrict__ adj,
    float* __restrict__ out)
{
  __shared__ u16 Klds[64 * 128];
  __shared__ u16 Vlds[128 * 64];
  __shared__ u64 Abits[64];

  const int b = blockIdx.x;
  const int qt = (b & 7) | ((b >> 5) << 3);
  const int hg = (b >> 3) & 3;
  const int h0 = hg * 2;
  const int t = threadIdx.x;
  const int w = t >> 6;
  const int lane = t & 63;
  const int qsub = w >> 1;
  const int hh = w & 1;
  const int h = h0 + hh;
  const int g = lane >> 4;
  const int qi = lane & 15;
  const int qbase = qt * 64;
  const int q_local = qsub * 16 + qi;
  const int qrow = qbase + q_local;

  const float SCL = 0.125f * 1.4426950408889634f;
  short8 qfrag[2];
  #pragma unroll
  for (int dc = 0; dc < 2; dc++) {
    const float* p = x1 + (size_t)qrow * QKD + h * DD + dc * 32 + g * 8;
    float4v a = *(const float4v*)p;
    float4v c = *(const float4v*)(p + 4);
    U8 r;
    r.u[0] = f2bf(a.x * SCL); r.u[1] = f2bf(a.y * SCL);
    r.u[2] = f2bf(a.z * SCL); r.u[3] = f2bf(a.w * SCL);
    r.u[4] = f2bf(c.x * SCL); r.u[5] = f2bf(c.y * SCL);
    r.u[6] = f2bf(c.z * SCL); r.u[7] = f2bf(c.w * SCL);
    qfrag[dc] = r.s;
  }

  const f32x4 zero = {0.f, 0.f, 0.f, 0.f};
  f32x4 Ot[4] = {zero, zero, zero, zero};
  float mrun = -1e30f;
  float lsum = 0.f;

  for (int kb = 0; kb < NN / 64; kb++) {
    const int k0 = kb * 64;
    __syncthreads();
    #pragma unroll
    for (int i = 0; i < 2; i++) {
      int s = t + i * 512;
      int row = s >> 4, c0 = (s & 15) * 8;
      int off = (row * 256 + c0 * 2) ^ ((row & 7) << 4);
      const float* p = x2f + (size_t)(k0 + row) * QKD + h0 * DD + c0;
      float4v a = *(const float4v*)p;
      float4v c = *(const float4v*)(p + 4);
      U8 r;
      r.u[0]=f2bf(a.x); r.u[1]=f2bf(a.y); r.u[2]=f2bf(a.z); r.u[3]=f2bf(a.w);
      r.u[4]=f2bf(c.x); r.u[5]=f2bf(c.y); r.u[6]=f2bf(c.z); r.u[7]=f2bf(c.w);
      *(short8*)((char*)Klds + off) = r.s;
    }
    {
      int vdg = t & 15, kp = t >> 4;
      int vd0 = vdg * 8, kk = kp * 2;
      u16 ua[8], ub[8];
      const float* pa = vf + (size_t)(k0 + kk) * QKD + h0 * DD + vd0;
      float4v a0 = *(const float4v*)pa;
      float4v a1 = *(const float4v*)(pa + 4);
      float4v b0 = *(const float4v*)(pa + QKD);
      float4v b1 = *(const float4v*)(pa + QKD + 4);
      ua[0]=f2bf(a0.x); ua[1]=f2bf(a0.y); ua[2]=f2bf(a0.z); ua[3]=f2bf(a0.w);
      ua[4]=f2bf(a1.x); ua[5]=f2bf(a1.y); ua[6]=f2bf(a1.z); ua[7]=f2bf(a1.w);
      ub[0]=f2bf(b0.x); ub[1]=f2bf(b0.y); ub[2]=f2bf(b0.z); ub[3]=f2bf(b0.w);
      ub[4]=f2bf(b1.x); ub[5]=f2bf(b1.y); ub[6]=f2bf(b1.z); ub[7]=f2bf(b1.w);
      #pragma unroll
      for (int j = 0; j < 8; j++) {
        u32 pk2 = (u32)ua[j] | ((u32)ub[j] << 16);
        int vd = vd0 + j;
        int off = (vd * 128 + kk * 2) ^ (((vd & 7) ^ ((vd >> 3) & 7)) << 4);
        *(u32*)((char*)Vlds + off) = pk2;
      }
    }
    {
      int row = t >> 3, c8 = t & 7;
      const int* ap = adj + (size_t)(qbase + row) * NN + k0 + c8 * 8;
      int4v a0 = *(const int4v*)ap;
      int4v a1 = *(const int4v*)(ap + 4);
      u32 byteval = (u32)(a0.x > 0)        | ((u32)(a0.y > 0) << 1) |
                    ((u32)(a0.z > 0) << 2) | ((u32)(a0.w > 0) << 3) |
                    ((u32)(a1.x > 0) << 4) | ((u32)(a1.y > 0) << 5) |
                    ((u32)(a1.z > 0) << 6) | ((u32)(a1.w > 0) << 7);
      ((unsigned char*)Abits)[row * 8 + c8] = (unsigned char)byteval;
    }
    __syncthreads();

    f32x4 st[4] = {zero, zero, zero, zero};
    #pragma unroll
    for (int tk = 0; tk < 4; tk++) {
      #pragma unroll
      for (int dc = 0; dc < 2; dc++) {
        int krow = tk * 16 + qi;
        int c = hh * 64 + dc * 32 + g * 8;
        int off = (krow * 256 + c * 2) ^ ((krow & 7) << 4);
        short8 af = *(const short8*)((char*)Klds + off);
        st[tk] = __builtin_amdgcn_mfma_f32_16x16x32_bf16(af, qfrag[dc], st[tk], 0, 0, 0);
      }
    }

    u64 bbm = Abits[q_local];
    u32 blo = (u32)bbm, bhi = (u32)(bbm >> 32);

    float tmax = -1e30f;
    #pragma unroll
    for (int tk = 0; tk < 4; tk++) {
      u32 half = (tk < 2) ? blo : bhi;
      int bb0 = (tk & 1) * 16 + g * 4;
      #pragma unroll
      for (int r = 0; r < 4; r++) {
        float s = st[tk][r];
        s = ((half >> (bb0 + r)) & 1u) ? s : -9e15f;
        st[tk][r] = s;
        tmax = fmaxf(tmax, s);
      }
    }
    tmax = fmaxf(tmax, __shfl_xor(tmax, 16));
    tmax = fmaxf(tmax, __shfl_xor(tmax, 32));
    float newm = fmaxf(mrun, tmax);
    float alpha = __builtin_amdgcn_exp2f(mrun - newm);
    mrun = newm;

    float psum = 0.f;
    u32 pk[8];
    #pragma unroll
    for (int tk = 0; tk < 4; tk++) {
      float p0 = __builtin_amdgcn_exp2f(st[tk][0] - newm);
      float p1 = __builtin_amdgcn_exp2f(st[tk][1] - newm);
      float p2 = __builtin_amdgcn_exp2f(st[tk][2] - newm);
      float p3 = __builtin_amdgcn_exp2f(st[tk][3] - newm);
      psum += (p0 + p1) + (p2 + p3);
      pk[tk * 2 + 0] = (u32)f2bf(p0) | ((u32)f2bf(p1) << 16);
      pk[tk * 2 + 1] = (u32)f2bf(p2) | ((u32)f2bf(p3) << 16);
    }
    psum += __shfl_xor(psum, 16);
    psum += __shfl_xor(psum, 32);
    lsum = lsum * alpha + psum;
    #pragma unroll
    for (int tv = 0; tv < 4; tv++) {
      Ot[tv][0] *= alpha; Ot[tv][1] *= alpha; Ot[tv][2] *= alpha; Ot[tv][3] *= alpha;
    }

    const int srcbase = qi + ((g & 1) << 5);
    #pragma unroll
    for (int kc = 0; kc < 2; kc++) {
      U4 pf;
      #pragma unroll
      for (int jp = 0; jp < 4; jp++) {
        int src = srcbase + ((jp >> 1) << 4);
        u32 va1 = (u32)__shfl((int)pk[4 * kc + (jp & 1)], src);
        u32 vb1 = (u32)__shfl((int)pk[4 * kc + 2 + (jp & 1)], src);
        pf.u[jp] = (g < 2) ? va1 : vb1;
      }
      #pragma unroll
      for (int tv = 0; tv < 4; tv++) {
        int vd = hh * 64 + tv * 16 + qi;
        int off = (vd * 128 + (kc * 32 + g * 8) * 2) ^ (((vd & 7) ^ ((vd >> 3) & 7)) << 4);
        short8 vfrag = *(const short8*)((char*)Vlds + off);
        Ot[tv] = __builtin_amdgcn_mfma_f32_16x16x32_bf16(vfrag, pf.s, Ot[tv], 0, 0, 0);
      }
    }
  }

  float inv = 1.0f / lsum;
  #pragma unroll
  for (int tv = 0; tv < 4; tv++) {
    float4v o;
    o.x = Ot[tv][0] * inv; o.y = Ot[tv][1] * inv;
    o.z = Ot[tv][2] * inv; o.w = Ot[tv][3] * inv;
    *(float4v*)(out + (size_t)qrow * QKD + h * DD + tv * 16 + g * 4) = o;
  }
}

extern "C" void kernel_launch(void* const* d_in, const int* in_sizes, int n_in,
                              void* d_out, int out_size, void* d_ws, size_t ws_size,
                              hipStream_t stream) {
  const float* x1 = (const float*)d_in[0];
  const float* x2 = (const float*)d_in[1];
  const float* v  = (const float*)d_in[2];
  const int* adj  = (const int*)d_in[3];
  float* out = (float*)d_out;

  const size_t szK = (size_t)NN * QKD * sizeof(u16);       // 4 MB
  const size_t szV = (size_t)NN * QKD * sizeof(u16);       // 4 MB
  const size_t szA = (size_t)NN * 64 * sizeof(u64);        // 2 MB
  const size_t need = szK + szV + szA;

  if (ws_size >= need && d_ws != nullptr) {
    u16* Kbt = (u16*)d_ws;
    u16* Vbt = (u16*)((char*)d_ws + szK);
    u64* Abg = (u64*)((char*)d_ws + szK + szV);
    cvt_kv<<<dim3(1024), dim3(256), 0, stream>>>(x2, v, Kbt, Vbt);
    pack_adj<<<dim3(NN), dim3(256), 0, stream>>>(adj, Abg);
    attn_fast<<<dim3(512), dim3(256), 0, stream>>>(x1, Abg, Kbt, Vbt, out);
  } else {
    attn_fallback<<<dim3(256), dim3(512), 0, stream>>>(x1, x2, v, adj, out);
  }
}

// Round 5
// 224.597 us; speedup vs baseline: 1.3292x; 1.0187x over previous
//
#include <hip/hip_runtime.h>

#define NN 4096
#define HEADS 8
#define DD 64
#define QKD 512

typedef __attribute__((ext_vector_type(8))) short short8;
typedef __attribute__((ext_vector_type(4))) float f32x4;
typedef __attribute__((ext_vector_type(4))) float float4v;
typedef __attribute__((ext_vector_type(4))) int int4v;
typedef unsigned int u32;
typedef unsigned short u16;
typedef unsigned long long u64;

union U8 { u16 u[8]; short8 s; };
union U4 { u32 u[4]; short8 s; };

__device__ __forceinline__ u16 f2bf(float f) {
  u32 u = __float_as_uint(f);
  u += 0x7fffu + ((u >> 16) & 1u);   // RNE
  return (u16)(u >> 16);
}

#define GLL(src, dst) __builtin_amdgcn_global_load_lds( \
    (const __attribute__((address_space(1))) void*)(src), \
    (__attribute__((address_space(3))) void*)(dst), 16, 0, 0)

// ============================================================================
// Fused prepass (single launch, 5120 blocks x 256):
//   b in [0,4096):      adj row b -> bitmask Abg[b*64 + kb] (u64, bit j = col kb*64+j)
//                       [R2 pack_adj body, verbatim]
//   b in [4096,4608):   x2 -> K bf16 tile images (pre-swizzled), tile j = b-4096
//                       [R2 cvt_kv K-path, verbatim]
//   b in [4608,5120):   v  -> V^T bf16 tile images (pre-swizzled), tile bb = b-4608
//                       [R2 cvt_kv V-path, verbatim]
// K tile (h,kb), 8 KB:  I[off] = K[kb*64+kr][h*64+d],  off = kr*128 + (d*2 ^ ((kr&7)<<4))
// V tile (h,kb), 8 KB:  I[off] = V[kb*64+k ][h*64+vd], off = vd*128 + (k*2 ^ ((vd&7)<<4))
// ============================================================================
__global__ __launch_bounds__(256) void prepass_fused(
    const float* __restrict__ x2, const float* __restrict__ v,
    const int* __restrict__ adj,
    u16* __restrict__ Kbt, u16* __restrict__ Vbt, u64* __restrict__ Abg)
{
  __shared__ u16 Vtmp[64][80];   // pad 80 -> 160B rows (16B aligned)
  const int b = blockIdx.x;
  const int t = threadIdx.x;

  if (b < 4096) {                      // ---------------- ADJ pack (1 row/block)
    const int row = b;
    const int w = t >> 6, lane = t & 63;
    const int* base = adj + (size_t)row * NN;
    #pragma unroll
    for (int i = 0; i < 16; i++) {
      int idx = w * 16 + i;
      int val = base[idx * 64 + lane];
      u64 m = __ballot(val > 0);
      if (lane == 0) Abg[(size_t)row * 64 + idx] = m;
    }
  } else if (b < 4608) {               // ---------------- K tiles
    const int j = b - 4096;            // tile id: h = j>>6, kb = j&63
    const int h = j >> 6, kb = j & 63;
    u16* dst = Kbt + (size_t)j * 4096;
    #pragma unroll
    for (int i = 0; i < 2; i++) {
      int c = t + i * 256;
      int off = c * 16;
      int kr = off >> 7;
      int db = (off & 127) ^ ((kr & 7) << 4);
      int d0 = db >> 1;
      const float* p = x2 + (size_t)(kb * 64 + kr) * QKD + h * DD + d0;
      float4v a0 = *(const float4v*)p;
      float4v a1 = *(const float4v*)(p + 4);
      U8 r;
      r.u[0] = f2bf(a0.x); r.u[1] = f2bf(a0.y); r.u[2] = f2bf(a0.z); r.u[3] = f2bf(a0.w);
      r.u[4] = f2bf(a1.x); r.u[5] = f2bf(a1.y); r.u[6] = f2bf(a1.z); r.u[7] = f2bf(a1.w);
      *(short8*)((char*)dst + off) = r.s;
    }
  } else {                             // ---------------- V tiles (transpose via LDS)
    const int bb = b - 4608;           // tile id: h = bb>>6, kb = bb&63
    const int h = bb >> 6, kb = bb & 63;
    {
      int k = t >> 2, j0 = (t & 3) * 16;
      const float* p = v + (size_t)(kb * 64 + k) * QKD + h * DD + j0;
      float4v a0 = *(const float4v*)p;
      float4v a1 = *(const float4v*)(p + 4);
      float4v a2 = *(const float4v*)(p + 8);
      float4v a3 = *(const float4v*)(p + 12);
      U8 r0, r1;
      r0.u[0] = f2bf(a0.x); r0.u[1] = f2bf(a0.y); r0.u[2] = f2bf(a0.z); r0.u[3] = f2bf(a0.w);
      r0.u[4] = f2bf(a1.x); r0.u[5] = f2bf(a1.y); r0.u[6] = f2bf(a1.z); r0.u[7] = f2bf(a1.w);
      r1.u[0] = f2bf(a2.x); r1.u[1] = f2bf(a2.y); r1.u[2] = f2bf(a2.z); r1.u[3] = f2bf(a2.w);
      r1.u[4] = f2bf(a3.x); r1.u[5] = f2bf(a3.y); r1.u[6] = f2bf(a3.z); r1.u[7] = f2bf(a3.w);
      *(short8*)(&Vtmp[k][j0]) = r0.s;
      *(short8*)(&Vtmp[k][j0 + 8]) = r1.s;
    }
    __syncthreads();
    u16* dst = Vbt + (size_t)bb * 4096;
    #pragma unroll
    for (int i = 0; i < 2; i++) {
      int c = t + i * 256;
      int off = c * 16;
      int vd = off >> 7;
      int kbyte = (off & 127) ^ ((vd & 7) << 4);
      int k0 = kbyte >> 1;
      U8 r;
      #pragma unroll
      for (int jj = 0; jj < 8; jj++) r.u[jj] = Vtmp[k0 + jj][vd];
      *(short8*)((char*)dst + off) = r.s;
    }
  }
}

// ============================================================================
// Main fused kernel [R2 attn_fast, VERBATIM — passed at 118 us].
// Grid 512 (64 q-tiles x 8 heads), 256 threads (4 waves), wave w owns q-rows
// qt*64 + w*16 + qi. Double-buffered LDS, global_load_lds staging from
// pre-swizzled tiles, one barrier per K-tile.
// ============================================================================
__global__ __launch_bounds__(256) void attn_fast(
    const float* __restrict__ x1,
    const u64* __restrict__ Abg,
    const u16* __restrict__ Kbt, const u16* __restrict__ Vbt,
    float* __restrict__ out)
{
  __shared__ u16 Klds[2][4096];
  __shared__ u16 Vlds[2][4096];

  const int b = blockIdx.x;
  const int widx = ((b & 7) << 6) | (b >> 3);   // XCD-chunked swizzle
  const int qt = widx >> 3;
  const int h = widx & 7;
  const int t = threadIdx.x;
  const int w = t >> 6;
  const int lane = t & 63;
  const int g = lane >> 4;
  const int qi = lane & 15;
  const int qrow = qt * 64 + w * 16 + qi;

  const u16* Ktiles = Kbt + (size_t)h * 64 * 4096;
  const u16* Vtiles = Vbt + (size_t)h * 64 * 4096;
  const u64* arow = Abg + (size_t)qrow * 64;

  // Q fragment (B operand): Q[qrow][h*64 + dc*32 + g*8 + e], pre-scaled (exp2 domain)
  const float SCL = 0.125f * 1.4426950408889634f;
  short8 qfrag[2];
  #pragma unroll
  for (int dc = 0; dc < 2; dc++) {
    const float* p = x1 + (size_t)qrow * QKD + h * DD + dc * 32 + g * 8;
    float4v a = *(const float4v*)p;
    float4v c = *(const float4v*)(p + 4);
    U8 r;
    r.u[0] = f2bf(a.x * SCL); r.u[1] = f2bf(a.y * SCL);
    r.u[2] = f2bf(a.z * SCL); r.u[3] = f2bf(a.w * SCL);
    r.u[4] = f2bf(c.x * SCL); r.u[5] = f2bf(c.y * SCL);
    r.u[6] = f2bf(c.z * SCL); r.u[7] = f2bf(c.w * SCL);
    qfrag[dc] = r.s;
  }

  const f32x4 zero = {0.f, 0.f, 0.f, 0.f};
  f32x4 Ot[4] = {zero, zero, zero, zero};
  float mrun = -1e30f;
  float lsum = 0.f;

  // stage tile 0 into buffer 0
  {
    const u16* sk = Ktiles + t * 8;
    const u16* sv = Vtiles + t * 8;
    u16* dk = &Klds[0][t * 8];
    u16* dv = &Vlds[0][t * 8];
    GLL(sk, dk);
    GLL(sk + 2048, dk + 2048);
    GLL(sv, dv);
    GLL(sv + 2048, dv + 2048);
  }
  u64 adjcur = arow[0];
  __syncthreads();

  int cur = 0;
  for (int kb = 0; kb < NN / 64; kb++) {
    // ---- issue next-tile staging (flies during compute, drained at the barrier)
    u64 adjnext = 0;
    if (kb < NN / 64 - 1) {
      const u16* sk = Ktiles + (size_t)(kb + 1) * 4096 + t * 8;
      const u16* sv = Vtiles + (size_t)(kb + 1) * 4096 + t * 8;
      u16* dk = &Klds[cur ^ 1][t * 8];
      u16* dv = &Vlds[cur ^ 1][t * 8];
      GLL(sk, dk);
      GLL(sk + 2048, dk + 2048);
      GLL(sv, dv);
      GLL(sv + 2048, dv + 2048);
      adjnext = arow[kb + 1];
    }

    // ---- S^T = K_tile . Q^T : lane holds S[q=qi][k = tk*16 + g*4 + r]
    const char* kbase = (const char*)Klds[cur];
    f32x4 st[4] = {zero, zero, zero, zero};
    #pragma unroll
    for (int tk = 0; tk < 4; tk++) {
      int krow = tk * 16 + qi;
      #pragma unroll
      for (int dc = 0; dc < 2; dc++) {
        int off = (krow * 128 + (dc * 32 + g * 8) * 2) ^ ((krow & 7) << 4);
        short8 af = *(const short8*)(kbase + off);
        st[tk] = __builtin_amdgcn_mfma_f32_16x16x32_bf16(af, qfrag[dc], st[tk], 0, 0, 0);
      }
    }

    u32 blo = (u32)adjcur, bhi = (u32)(adjcur >> 32);

    // ---- mask + online softmax (exp2 domain)
    float tmax = -1e30f;
    #pragma unroll
    for (int tk = 0; tk < 4; tk++) {
      u32 half = (tk < 2) ? blo : bhi;
      int bb0 = (tk & 1) * 16 + g * 4;
      #pragma unroll
      for (int r = 0; r < 4; r++) {
        float s = st[tk][r];
        s = ((half >> (bb0 + r)) & 1u) ? s : -9e15f;
        st[tk][r] = s;
        tmax = fmaxf(tmax, s);
      }
    }
    tmax = fmaxf(tmax, __shfl_xor(tmax, 16));
    tmax = fmaxf(tmax, __shfl_xor(tmax, 32));
    float newm = fmaxf(mrun, tmax);
    float alpha = __builtin_amdgcn_exp2f(mrun - newm);
    mrun = newm;

    float psum = 0.f;
    u32 pk[8];
    #pragma unroll
    for (int tk = 0; tk < 4; tk++) {
      float p0 = __builtin_amdgcn_exp2f(st[tk][0] - newm);
      float p1 = __builtin_amdgcn_exp2f(st[tk][1] - newm);
      float p2 = __builtin_amdgcn_exp2f(st[tk][2] - newm);
      float p3 = __builtin_amdgcn_exp2f(st[tk][3] - newm);
      psum += (p0 + p1) + (p2 + p3);
      pk[tk * 2 + 0] = (u32)f2bf(p0) | ((u32)f2bf(p1) << 16);
      pk[tk * 2 + 1] = (u32)f2bf(p2) | ((u32)f2bf(p3) << 16);
    }
    psum += __shfl_xor(psum, 16);
    psum += __shfl_xor(psum, 32);
    lsum = lsum * alpha + psum;
    #pragma unroll
    for (int tv = 0; tv < 4; tv++) {
      Ot[tv][0] *= alpha; Ot[tv][1] *= alpha; Ot[tv][2] *= alpha; Ot[tv][3] *= alpha;
    }

    // ---- redistribute P to B-frag layout + PV (out^T accumulation)
    const char* vbase = (const char*)Vlds[cur];
    const int srcbase = qi + ((g & 1) << 5);
    #pragma unroll
    for (int kc = 0; kc < 2; kc++) {
      U4 pf;
      #pragma unroll
      for (int jp = 0; jp < 4; jp++) {
        int src = srcbase + ((jp >> 1) << 4);
        u32 va1 = (u32)__shfl((int)pk[4 * kc + (jp & 1)], src);
        u32 vb1 = (u32)__shfl((int)pk[4 * kc + 2 + (jp & 1)], src);
        pf.u[jp] = (g < 2) ? va1 : vb1;
      }
      #pragma unroll
      for (int tv = 0; tv < 4; tv++) {
        int vd = tv * 16 + qi;
        int off = (vd * 128 + (kc * 32 + g * 8) * 2) ^ ((vd & 7) << 4);
        short8 vfrag = *(const short8*)(vbase + off);
        Ot[tv] = __builtin_amdgcn_mfma_f32_16x16x32_bf16(vfrag, pf.s, Ot[tv], 0, 0, 0);
      }
    }

    __syncthreads();   // drains in-flight global_load_lds + barrier
    adjcur = adjnext;
    cur ^= 1;
  }

  // ---- epilogue
  float inv = 1.0f / lsum;
  #pragma unroll
  for (int tv = 0; tv < 4; tv++) {
    float4v o;
    o.x = Ot[tv][0] * inv; o.y = Ot[tv][1] * inv;
    o.z = Ot[tv][2] * inv; o.w = Ot[tv][3] * inv;
    *(float4v*)(out + (size_t)qrow * QKD + h * DD + tv * 16 + g * 4) = o;
  }
}

// ============================================================================
// Fallback (no workspace): known-good round-1 kernel, f32 inputs in-kernel.
// ============================================================================
__global__ __launch_bounds__(512) void attn_fallback(
    const float* __restrict__ x1, const float* __restrict__ x2f,
    const float* __restrict__ vf, const int* __restrict__ adj,
    float* __restrict__ out)
{
  __shared__ u16 Klds[64 * 128];
  __shared__ u16 Vlds[128 * 64];
  __shared__ u64 Abits[64];

  const int b = blockIdx.x;
  const int qt = (b & 7) | ((b >> 5) << 3);
  const int hg = (b >> 3) & 3;
  const int h0 = hg * 2;
  const int t = threadIdx.x;
  const int w = t >> 6;
  const int lane = t & 63;
  const int qsub = w >> 1;
  const int hh = w & 1;
  const int h = h0 + hh;
  const int g = lane >> 4;
  const int qi = lane & 15;
  const int qbase = qt * 64;
  const int q_local = qsub * 16 + qi;
  const int qrow = qbase + q_local;

  const float SCL = 0.125f * 1.4426950408889634f;
  short8 qfrag[2];
  #pragma unroll
  for (int dc = 0; dc < 2; dc++) {
    const float* p = x1 + (size_t)qrow * QKD + h * DD + dc * 32 + g * 8;
    float4v a = *(const float4v*)p;
    float4v c = *(const float4v*)(p + 4);
    U8 r;
    r.u[0] = f2bf(a.x * SCL); r.u[1] = f2bf(a.y * SCL);
    r.u[2] = f2bf(a.z * SCL); r.u[3] = f2bf(a.w * SCL);
    r.u[4] = f2bf(c.x * SCL); r.u[5] = f2bf(c.y * SCL);
    r.u[6] = f2bf(c.z * SCL); r.u[7] = f2bf(c.w * SCL);
    qfrag[dc] = r.s;
  }

  const f32x4 zero = {0.f, 0.f, 0.f, 0.f};
  f32x4 Ot[4] = {zero, zero, zero, zero};
  float mrun = -1e30f;
  float lsum = 0.f;

  for (int kb = 0; kb < NN / 64; kb++) {
    const int k0 = kb * 64;
    __syncthreads();
    #pragma unroll
    for (int i = 0; i < 2; i++) {
      int s = t + i * 512;
      int row = s >> 4, c0 = (s & 15) * 8;
      int off = (row * 256 + c0 * 2) ^ ((row & 7) << 4);
      const float* p = x2f + (size_t)(k0 + row) * QKD + h0 * DD + c0;
      float4v a = *(const float4v*)p;
      float4v c = *(const float4v*)(p + 4);
      U8 r;
      r.u[0]=f2bf(a.x); r.u[1]=f2bf(a.y); r.u[2]=f2bf(a.z); r.u[3]=f2bf(a.w);
      r.u[4]=f2bf(c.x); r.u[5]=f2bf(c.y); r.u[6]=f2bf(c.z); r.u[7]=f2bf(c.w);
      *(short8*)((char*)Klds + off) = r.s;
    }
    {
      int vdg = t & 15, kp = t >> 4;
      int vd0 = vdg * 8, kk = kp * 2;
      u16 ua[8], ub[8];
      const float* pa = vf + (size_t)(k0 + kk) * QKD + h0 * DD + vd0;
      float4v a0 = *(const float4v*)pa;
      float4v a1 = *(const float4v*)(pa + 4);
      float4v b0 = *(const float4v*)(pa + QKD);
      float4v b1 = *(const float4v*)(pa + QKD + 4);
      ua[0]=f2bf(a0.x); ua[1]=f2bf(a0.y); ua[2]=f2bf(a0.z); ua[3]=f2bf(a0.w);
      ua[4]=f2bf(a1.x); ua[5]=f2bf(a1.y); ua[6]=f2bf(a1.z); ua[7]=f2bf(a1.w);
      ub[0]=f2bf(b0.x); ub[1]=f2bf(b0.y); ub[2]=f2bf(b0.z); ub[3]=f2bf(b0.w);
      ub[4]=f2bf(b1.x); ub[5]=f2bf(b1.y); ub[6]=f2bf(b1.z); ub[7]=f2bf(b1.w);
      #pragma unroll
      for (int j = 0; j < 8; j++) {
        u32 pk2 = (u32)ua[j] | ((u32)ub[j] << 16);
        int vd = vd0 + j;
        int off = (vd * 128 + kk * 2) ^ (((vd & 7) ^ ((vd >> 3) & 7)) << 4);
        *(u32*)((char*)Vlds + off) = pk2;
      }
    }
    {
      int row = t >> 3, c8 = t & 7;
      const int* ap = adj + (size_t)(qbase + row) * NN + k0 + c8 * 8;
      int4v a0 = *(const int4v*)ap;
      int4v a1 = *(const int4v*)(ap + 4);
      u32 byteval = (u32)(a0.x > 0)        | ((u32)(a0.y > 0) << 1) |
                    ((u32)(a0.z > 0) << 2) | ((u32)(a0.w > 0) << 3) |
                    ((u32)(a1.x > 0) << 4) | ((u32)(a1.y > 0) << 5) |
                    ((u32)(a1.z > 0) << 6) | ((u32)(a1.w > 0) << 7);
      ((unsigned char*)Abits)[row * 8 + c8] = (unsigned char)byteval;
    }
    __syncthreads();

    f32x4 st[4] = {zero, zero, zero, zero};
    #pragma unroll
    for (int tk = 0; tk < 4; tk++) {
      #pragma unroll
      for (int dc = 0; dc < 2; dc++) {
        int krow = tk * 16 + qi;
        int c = hh * 64 + dc * 32 + g * 8;
        int off = (krow * 256 + c * 2) ^ ((krow & 7) << 4);
        short8 af = *(const short8*)((char*)Klds + off);
        st[tk] = __builtin_amdgcn_mfma_f32_16x16x32_bf16(af, qfrag[dc], st[tk], 0, 0, 0);
      }
    }

    u64 bbm = Abits[q_local];
    u32 blo = (u32)bbm, bhi = (u32)(bbm >> 32);

    float tmax = -1e30f;
    #pragma unroll
    for (int tk = 0; tk < 4; tk++) {
      u32 half = (tk < 2) ? blo : bhi;
      int bb0 = (tk & 1) * 16 + g * 4;
      #pragma unroll
      for (int r = 0; r < 4; r++) {
        float s = st[tk][r];
        s = ((half >> (bb0 + r)) & 1u) ? s : -9e15f;
        st[tk][r] = s;
        tmax = fmaxf(tmax, s);
      }
    }
    tmax = fmaxf(tmax, __shfl_xor(tmax, 16));
    tmax = fmaxf(tmax, __shfl_xor(tmax, 32));
    float newm = fmaxf(mrun, tmax);
    float alpha = __builtin_amdgcn_exp2f(mrun - newm);
    mrun = newm;

    float psum = 0.f;
    u32 pk[8];
    #pragma unroll
    for (int tk = 0; tk < 4; tk++) {
      float p0 = __builtin_amdgcn_exp2f(st[tk][0] - newm);
      float p1 = __builtin_amdgcn_exp2f(st[tk][1] - newm);
      float p2 = __builtin_amdgcn_exp2f(st[tk][2] - newm);
      float p3 = __builtin_amdgcn_exp2f(st[tk][3] - newm);
      psum += (p0 + p1) + (p2 + p3);
      pk[tk * 2 + 0] = (u32)f2bf(p0) | ((u32)f2bf(p1) << 16);
      pk[tk * 2 + 1] = (u32)f2bf(p2) | ((u32)f2bf(p3) << 16);
    }
    psum += __shfl_xor(psum, 16);
    psum += __shfl_xor(psum, 32);
    lsum = lsum * alpha + psum;
    #pragma unroll
    for (int tv = 0; tv < 4; tv++) {
      Ot[tv][0] *= alpha; Ot[tv][1] *= alpha; Ot[tv][2] *= alpha; Ot[tv][3] *= alpha;
    }

    const int srcbase = qi + ((g & 1) << 5);
    #pragma unroll
    for (int kc = 0; kc < 2; kc++) {
      U4 pf;
      #pragma unroll
      for (int jp = 0; jp < 4; jp++) {
        int src = srcbase + ((jp >> 1) << 4);
        u32 va1 = (u32)__shfl((int)pk[4 * kc + (jp & 1)], src);
        u32 vb1 = (u32)__shfl((int)pk[4 * kc + 2 + (jp & 1)], src);
        pf.u[jp] = (g < 2) ? va1 : vb1;
      }
      #pragma unroll
      for (int tv = 0; tv < 4; tv++) {
        int vd = hh * 64 + tv * 16 + qi;
        int off = (vd * 128 + (kc * 32 + g * 8) * 2) ^ (((vd & 7) ^ ((vd >> 3) & 7)) << 4);
        short8 vfrag = *(const short8*)((char*)Vlds + off);
        Ot[tv] = __builtin_amdgcn_mfma_f32_16x16x32_bf16(vfrag, pf.s, Ot[tv], 0, 0, 0);
      }
    }
  }

  float inv = 1.0f / lsum;
  #pragma unroll
  for (int tv = 0; tv < 4; tv++) {
    float4v o;
    o.x = Ot[tv][0] * inv; o.y = Ot[tv][1] * inv;
    o.z = Ot[tv][2] * inv; o.w = Ot[tv][3] * inv;
    *(float4v*)(out + (size_t)qrow * QKD + h * DD + tv * 16 + g * 4) = o;
  }
}

extern "C" void kernel_launch(void* const* d_in, const int* in_sizes, int n_in,
                              void* d_out, int out_size, void* d_ws, size_t ws_size,
                              hipStream_t stream) {
  const float* x1 = (const float*)d_in[0];
  const float* x2 = (const float*)d_in[1];
  const float* v  = (const float*)d_in[2];
  const int* adj  = (const int*)d_in[3];
  float* out = (float*)d_out;

  const size_t szK = (size_t)512 * 4096 * sizeof(u16);     // 4 MB (512 tiles x 8KB)
  const size_t szV = szK;                                   // 4 MB
  const size_t szA = (size_t)NN * 64 * sizeof(u64);         // 2 MB
  const size_t need = szK + szV + szA;

  if (ws_size >= need && d_ws != nullptr) {
    u16* Kbt = (u16*)d_ws;
    u16* Vbt = (u16*)((char*)d_ws + szK);
    u64* Abg = (u64*)((char*)d_ws + szK + szV);
    prepass_fused<<<dim3(5120), dim3(256), 0, stream>>>(x2, v, adj, Kbt, Vbt, Abg);
    attn_fast<<<dim3(512), dim3(256), 0, stream>>>(x1, Abg, Kbt, Vbt, out);
  } else {
    attn_fallback<<<dim3(256), dim3(512), 0, stream>>>(x1, x2, v, adj, out);
  }
}

// Round 6
// 209.468 us; speedup vs baseline: 1.4252x; 1.0722x over previous
//
#include <hip/hip_runtime.h>

#define NN 4096
#define HEADS 8
#define DD 64
#define QKD 512

typedef __attribute__((ext_vector_type(8))) short short8;
typedef __attribute__((ext_vector_type(4))) float f32x4;
typedef __attribute__((ext_vector_type(4))) float float4v;
typedef __attribute__((ext_vector_type(4))) int int4v;
typedef unsigned int u32;
typedef unsigned short u16;
typedef unsigned long long u64;

union U8 { u16 u[8]; short8 s; };
union U4 { u32 u[4]; short8 s; };

__device__ __forceinline__ u16 f2bf(float f) {
  u32 u = __float_as_uint(f);
  u += 0x7fffu + ((u >> 16) & 1u);   // RNE
  return (u16)(u >> 16);
}

__device__ __forceinline__ u32 cvtpk(float lo, float hi) {   // bf16(lo) | bf16(hi)<<16, RNE
  u32 d;
  asm("v_cvt_pk_bf16_f32 %0, %1, %2" : "=v"(d) : "v"(lo), "v"(hi));
  return d;
}

#define GLL(src, dst) __builtin_amdgcn_global_load_lds( \
    (const __attribute__((address_space(1))) void*)(src), \
    (__attribute__((address_space(3))) void*)(dst), 16, 0, 0)

// ============================================================================
// Fused prepass (single launch, 5120 blocks x 256):
//   b in [0,4096):      adj row b -> bitmask Abg[b*64 + m] (u64, bit c = col m*64+c)
//                       VECTORIZED: 16B/lane int4 loads, LDS byte assembly.
//   b in [4096,4608):   x2 -> K bf16 tile images (pre-swizzled)   [R5 verbatim]
//   b in [4608,5120):   v  -> V^T bf16 tile images (pre-swizzled) [R5 verbatim]
// K tile (h,kb), 8 KB:  I[off] = K[kb*64+kr][h*64+d],  off = kr*128 + (d*2 ^ ((kr&7)<<4))
// V tile (h,kb), 8 KB:  I[off] = V[kb*64+k ][h*64+vd], off = vd*128 + (k*2 ^ ((vd&7)<<4))
// ============================================================================
__global__ __launch_bounds__(256) void prepass_fused(
    const float* __restrict__ x2, const float* __restrict__ v,
    const int* __restrict__ adj,
    u16* __restrict__ Kbt, u16* __restrict__ Vbt, u64* __restrict__ Abg)
{
  __shared__ u16 Vtmp[64][80];   // V path: pad 80 -> 160B rows; adj path reuses 512B
  const int b = blockIdx.x;
  const int t = threadIdx.x;

  if (b < 4096) {                      // ---------------- ADJ pack (1 row/block)
    const int row = b;
    const int* src = adj + (size_t)row * NN;
    // thread t covers cols 16t..16t+15 (four int4 loads = 64B/lane)
    int4v a0 = *(const int4v*)(src + t * 16);
    int4v a1 = *(const int4v*)(src + t * 16 + 4);
    int4v a2 = *(const int4v*)(src + t * 16 + 8);
    int4v a3 = *(const int4v*)(src + t * 16 + 12);
    u32 bits =
        (u32)(a0.x > 0)         | ((u32)(a0.y > 0) << 1)  |
        ((u32)(a0.z > 0) << 2)  | ((u32)(a0.w > 0) << 3)  |
        ((u32)(a1.x > 0) << 4)  | ((u32)(a1.y > 0) << 5)  |
        ((u32)(a1.z > 0) << 6)  | ((u32)(a1.w > 0) << 7)  |
        ((u32)(a2.x > 0) << 8)  | ((u32)(a2.y > 0) << 9)  |
        ((u32)(a2.z > 0) << 10) | ((u32)(a2.w > 0) << 11) |
        ((u32)(a3.x > 0) << 12) | ((u32)(a3.y > 0) << 13) |
        ((u32)(a3.z > 0) << 14) | ((u32)(a3.w > 0) << 15);
    unsigned char* AB = (unsigned char*)Vtmp;          // 512 B bit-image of the row
    *(u16*)(AB + t * 2) = (u16)bits;                   // bytes 2t,2t+1 = cols 16t..16t+15
    __syncthreads();
    if (t < 64) {
      u64 m = *(const u64*)(AB + t * 8);               // word t = cols 64t..64t+63 (LE)
      Abg[(size_t)row * 64 + t] = m;
    }
  } else if (b < 4608) {               // ---------------- K tiles [R5 verbatim]
    const int j = b - 4096;
    const int h = j >> 6, kb = j & 63;
    u16* dst = Kbt + (size_t)j * 4096;
    #pragma unroll
    for (int i = 0; i < 2; i++) {
      int c = t + i * 256;
      int off = c * 16;
      int kr = off >> 7;
      int db = (off & 127) ^ ((kr & 7) << 4);
      int d0 = db >> 1;
      const float* p = x2 + (size_t)(kb * 64 + kr) * QKD + h * DD + d0;
      float4v a0 = *(const float4v*)p;
      float4v a1 = *(const float4v*)(p + 4);
      U8 r;
      r.u[0] = f2bf(a0.x); r.u[1] = f2bf(a0.y); r.u[2] = f2bf(a0.z); r.u[3] = f2bf(a0.w);
      r.u[4] = f2bf(a1.x); r.u[5] = f2bf(a1.y); r.u[6] = f2bf(a1.z); r.u[7] = f2bf(a1.w);
      *(short8*)((char*)dst + off) = r.s;
    }
  } else {                             // ---------------- V tiles [R5 verbatim]
    const int bb = b - 4608;
    const int h = bb >> 6, kb = bb & 63;
    {
      int k = t >> 2, j0 = (t & 3) * 16;
      const float* p = v + (size_t)(kb * 64 + k) * QKD + h * DD + j0;
      float4v a0 = *(const float4v*)p;
      float4v a1 = *(const float4v*)(p + 4);
      float4v a2 = *(const float4v*)(p + 8);
      float4v a3 = *(const float4v*)(p + 12);
      U8 r0, r1;
      r0.u[0] = f2bf(a0.x); r0.u[1] = f2bf(a0.y); r0.u[2] = f2bf(a0.z); r0.u[3] = f2bf(a0.w);
      r0.u[4] = f2bf(a1.x); r0.u[5] = f2bf(a1.y); r0.u[6] = f2bf(a1.z); r0.u[7] = f2bf(a1.w);
      r1.u[0] = f2bf(a2.x); r1.u[1] = f2bf(a2.y); r1.u[2] = f2bf(a2.z); r1.u[3] = f2bf(a2.w);
      r1.u[4] = f2bf(a3.x); r1.u[5] = f2bf(a3.y); r1.u[6] = f2bf(a3.z); r1.u[7] = f2bf(a3.w);
      *(short8*)(&Vtmp[k][j0]) = r0.s;
      *(short8*)(&Vtmp[k][j0 + 8]) = r1.s;
    }
    __syncthreads();
    u16* dst = Vbt + (size_t)bb * 4096;
    #pragma unroll
    for (int i = 0; i < 2; i++) {
      int c = t + i * 256;
      int off = c * 16;
      int vd = off >> 7;
      int kbyte = (off & 127) ^ ((vd & 7) << 4);
      int k0 = kbyte >> 1;
      U8 r;
      #pragma unroll
      for (int jj = 0; jj < 8; jj++) r.u[jj] = Vtmp[k0 + jj][vd];
      *(short8*)((char*)dst + off) = r.s;
    }
  }
}

// ============================================================================
// Main fused kernel [R5 structure; + exact defer-max, cvt_pk P-pack, max-tree,
// setprio around MFMA clusters]. Grid 512 (64 q-tiles x 8 heads), 256 thr.
// ============================================================================
__global__ __launch_bounds__(256) void attn_fast(
    const float* __restrict__ x1,
    const u64* __restrict__ Abg,
    const u16* __restrict__ Kbt, const u16* __restrict__ Vbt,
    float* __restrict__ out)
{
  __shared__ u16 Klds[2][4096];
  __shared__ u16 Vlds[2][4096];

  const int b = blockIdx.x;
  const int widx = ((b & 7) << 6) | (b >> 3);   // XCD-chunked swizzle
  const int qt = widx >> 3;
  const int h = widx & 7;
  const int t = threadIdx.x;
  const int w = t >> 6;
  const int lane = t & 63;
  const int g = lane >> 4;
  const int qi = lane & 15;
  const int qrow = qt * 64 + w * 16 + qi;

  const u16* Ktiles = Kbt + (size_t)h * 64 * 4096;
  const u16* Vtiles = Vbt + (size_t)h * 64 * 4096;
  const u64* arow = Abg + (size_t)qrow * 64;

  const float SCL = 0.125f * 1.4426950408889634f;
  short8 qfrag[2];
  #pragma unroll
  for (int dc = 0; dc < 2; dc++) {
    const float* p = x1 + (size_t)qrow * QKD + h * DD + dc * 32 + g * 8;
    float4v a = *(const float4v*)p;
    float4v c = *(const float4v*)(p + 4);
    U8 r;
    r.u[0] = f2bf(a.x * SCL); r.u[1] = f2bf(a.y * SCL);
    r.u[2] = f2bf(a.z * SCL); r.u[3] = f2bf(a.w * SCL);
    r.u[4] = f2bf(c.x * SCL); r.u[5] = f2bf(c.y * SCL);
    r.u[6] = f2bf(c.z * SCL); r.u[7] = f2bf(c.w * SCL);
    qfrag[dc] = r.s;
  }

  const f32x4 zero = {0.f, 0.f, 0.f, 0.f};
  f32x4 Ot[4] = {zero, zero, zero, zero};
  float mrun = -1e30f;
  float lsum = 0.f;

  {
    const u16* sk = Ktiles + t * 8;
    const u16* sv = Vtiles + t * 8;
    u16* dk = &Klds[0][t * 8];
    u16* dv = &Vlds[0][t * 8];
    GLL(sk, dk);
    GLL(sk + 2048, dk + 2048);
    GLL(sv, dv);
    GLL(sv + 2048, dv + 2048);
  }
  u64 adjcur = arow[0];
  __syncthreads();

  int cur = 0;
  for (int kb = 0; kb < NN / 64; kb++) {
    u64 adjnext = 0;
    if (kb < NN / 64 - 1) {
      const u16* sk = Ktiles + (size_t)(kb + 1) * 4096 + t * 8;
      const u16* sv = Vtiles + (size_t)(kb + 1) * 4096 + t * 8;
      u16* dk = &Klds[cur ^ 1][t * 8];
      u16* dv = &Vlds[cur ^ 1][t * 8];
      GLL(sk, dk);
      GLL(sk + 2048, dk + 2048);
      GLL(sv, dv);
      GLL(sv + 2048, dv + 2048);
      adjnext = arow[kb + 1];
    }

    // ---- S^T = K_tile . Q^T
    const char* kbase = (const char*)Klds[cur];
    f32x4 st[4] = {zero, zero, zero, zero};
    __builtin_amdgcn_s_setprio(1);
    #pragma unroll
    for (int tk = 0; tk < 4; tk++) {
      int krow = tk * 16 + qi;
      #pragma unroll
      for (int dc = 0; dc < 2; dc++) {
        int off = (krow * 128 + (dc * 32 + g * 8) * 2) ^ ((krow & 7) << 4);
        short8 af = *(const short8*)(kbase + off);
        st[tk] = __builtin_amdgcn_mfma_f32_16x16x32_bf16(af, qfrag[dc], st[tk], 0, 0, 0);
      }
    }
    __builtin_amdgcn_s_setprio(0);

    u32 blo = (u32)adjcur, bhi = (u32)(adjcur >> 32);

    // ---- mask + tree max
    #pragma unroll
    for (int tk = 0; tk < 4; tk++) {
      u32 half = (tk < 2) ? blo : bhi;
      int bb0 = (tk & 1) * 16 + g * 4;
      #pragma unroll
      for (int r = 0; r < 4; r++) {
        float s = st[tk][r];
        st[tk][r] = ((half >> (bb0 + r)) & 1u) ? s : -9e15f;
      }
    }
    float t0 = fmaxf(fmaxf(st[0][0], st[0][1]), fmaxf(st[0][2], st[0][3]));
    float t1 = fmaxf(fmaxf(st[1][0], st[1][1]), fmaxf(st[1][2], st[1][3]));
    float t2 = fmaxf(fmaxf(st[2][0], st[2][1]), fmaxf(st[2][2], st[2][3]));
    float t3 = fmaxf(fmaxf(st[3][0], st[3][1]), fmaxf(st[3][2], st[3][3]));
    float tmax = fmaxf(fmaxf(t0, t1), fmaxf(t2, t3));
    tmax = fmaxf(tmax, __shfl_xor(tmax, 16));
    tmax = fmaxf(tmax, __shfl_xor(tmax, 32));

    // ---- exact defer-max: alpha==1 identity when all rows stable
    if (!__all(tmax <= mrun)) {
      const float newm = fmaxf(mrun, tmax);
      const float alpha = __builtin_amdgcn_exp2f(mrun - newm);
      lsum *= alpha;
      #pragma unroll
      for (int tv = 0; tv < 4; tv++) {
        Ot[tv][0] *= alpha; Ot[tv][1] *= alpha; Ot[tv][2] *= alpha; Ot[tv][3] *= alpha;
      }
      mrun = newm;
    }

    float psum = 0.f;
    u32 pk[8];
    #pragma unroll
    for (int tk = 0; tk < 4; tk++) {
      float p0 = __builtin_amdgcn_exp2f(st[tk][0] - mrun);
      float p1 = __builtin_amdgcn_exp2f(st[tk][1] - mrun);
      float p2 = __builtin_amdgcn_exp2f(st[tk][2] - mrun);
      float p3 = __builtin_amdgcn_exp2f(st[tk][3] - mrun);
      psum += (p0 + p1) + (p2 + p3);
      pk[tk * 2 + 0] = cvtpk(p0, p1);
      pk[tk * 2 + 1] = cvtpk(p2, p3);
    }
    psum += __shfl_xor(psum, 16);
    psum += __shfl_xor(psum, 32);
    lsum += psum;

    // ---- redistribute P to B-frag layout + PV (out^T accumulation)
    const char* vbase = (const char*)Vlds[cur];
    const int srcbase = qi + ((g & 1) << 5);
    #pragma unroll
    for (int kc = 0; kc < 2; kc++) {
      U4 pf;
      #pragma unroll
      for (int jp = 0; jp < 4; jp++) {
        int src = srcbase + ((jp >> 1) << 4);
        u32 va1 = (u32)__shfl((int)pk[4 * kc + (jp & 1)], src);
        u32 vb1 = (u32)__shfl((int)pk[4 * kc + 2 + (jp & 1)], src);
        pf.u[jp] = (g < 2) ? va1 : vb1;
      }
      __builtin_amdgcn_s_setprio(1);
      #pragma unroll
      for (int tv = 0; tv < 4; tv++) {
        int vd = tv * 16 + qi;
        int off = (vd * 128 + (kc * 32 + g * 8) * 2) ^ ((vd & 7) << 4);
        short8 vfrag = *(const short8*)(vbase + off);
        Ot[tv] = __builtin_amdgcn_mfma_f32_16x16x32_bf16(vfrag, pf.s, Ot[tv], 0, 0, 0);
      }
      __builtin_amdgcn_s_setprio(0);
    }

    __syncthreads();   // drains in-flight global_load_lds + barrier
    adjcur = adjnext;
    cur ^= 1;
  }

  // ---- epilogue
  float inv = 1.0f / lsum;
  #pragma unroll
  for (int tv = 0; tv < 4; tv++) {
    float4v o;
    o.x = Ot[tv][0] * inv; o.y = Ot[tv][1] * inv;
    o.z = Ot[tv][2] * inv; o.w = Ot[tv][3] * inv;
    *(float4v*)(out + (size_t)qrow * QKD + h * DD + tv * 16 + g * 4) = o;
  }
}

// ============================================================================
// Fallback (no workspace): known-good round-1 kernel, f32 inputs in-kernel.
// ============================================================================
__global__ __launch_bounds__(512) void attn_fallback(
    const float* __restrict__ x1, const float* __restrict__ x2f,
    const float* __restrict__ vf, const int* __restrict__ adj,
    float* __restrict__ out)
{
  __shared__ u16 Klds[64 * 128];
  __shared__ u16 Vlds[128 * 64];
  __shared__ u64 Abits[64];

  const int b = blockIdx.x;
  const int qt = (b & 7) | ((b >> 5) << 3);
  const int hg = (b >> 3) & 3;
  const int h0 = hg * 2;
  const int t = threadIdx.x;
  const int w = t >> 6;
  const int lane = t & 63;
  const int qsub = w >> 1;
  const int hh = w & 1;
  const int h = h0 + hh;
  const int g = lane >> 4;
  const int qi = lane & 15;
  const int qbase = qt * 64;
  const int q_local = qsub * 16 + qi;
  const int qrow = qbase + q_local;

  const float SCL = 0.125f * 1.4426950408889634f;
  short8 qfrag[2];
  #pragma unroll
  for (int dc = 0; dc < 2; dc++) {
    const float* p = x1 + (size_t)qrow * QKD + h * DD + dc * 32 + g * 8;
    float4v a = *(const float4v*)p;
    float4v c = *(const float4v*)(p + 4);
    U8 r;
    r.u[0] = f2bf(a.x * SCL); r.u[1] = f2bf(a.y * SCL);
    r.u[2] = f2bf(a.z * SCL); r.u[3] = f2bf(a.w * SCL);
    r.u[4] = f2bf(c.x * SCL); r.u[5] = f2bf(c.y * SCL);
    r.u[6] = f2bf(c.z * SCL); r.u[7] = f2bf(c.w * SCL);
    qfrag[dc] = r.s;
  }

  const f32x4 zero = {0.f, 0.f, 0.f, 0.f};
  f32x4 Ot[4] = {zero, zero, zero, zero};
  float mrun = -1e30f;
  float lsum = 0.f;

  for (int kb = 0; kb < NN / 64; kb++) {
    const int k0 = kb * 64;
    __syncthreads();
    #pragma unroll
    for (int i = 0; i < 2; i++) {
      int s = t + i * 512;
      int row = s >> 4, c0 = (s & 15) * 8;
      int off = (row * 256 + c0 * 2) ^ ((row & 7) << 4);
      const float* p = x2f + (size_t)(k0 + row) * QKD + h0 * DD + c0;
      float4v a = *(const float4v*)p;
      float4v c = *(const float4v*)(p + 4);
      U8 r;
      r.u[0]=f2bf(a.x); r.u[1]=f2bf(a.y); r.u[2]=f2bf(a.z); r.u[3]=f2bf(a.w);
      r.u[4]=f2bf(c.x); r.u[5]=f2bf(c.y); r.u[6]=f2bf(c.z); r.u[7]=f2bf(c.w);
      *(short8*)((char*)Klds + off) = r.s;
    }
    {
      int vdg = t & 15, kp = t >> 4;
      int vd0 = vdg * 8, kk = kp * 2;
      u16 ua[8], ub[8];
      const float* pa = vf + (size_t)(k0 + kk) * QKD + h0 * DD + vd0;
      float4v a0 = *(const float4v*)pa;
      float4v a1 = *(const float4v*)(pa + 4);
      float4v b0 = *(const float4v*)(pa + QKD);
      float4v b1 = *(const float4v*)(pa + QKD + 4);
      ua[0]=f2bf(a0.x); ua[1]=f2bf(a0.y); ua[2]=f2bf(a0.z); ua[3]=f2bf(a0.w);
      ua[4]=f2bf(a1.x); ua[5]=f2bf(a1.y); ua[6]=f2bf(a1.z); ua[7]=f2bf(a1.w);
      ub[0]=f2bf(b0.x); ub[1]=f2bf(b0.y); ub[2]=f2bf(b0.z); ub[3]=f2bf(b0.w);
      ub[4]=f2bf(b1.x); ub[5]=f2bf(b1.y); ub[6]=f2bf(b1.z); ub[7]=f2bf(b1.w);
      #pragma unroll
      for (int j = 0; j < 8; j++) {
        u32 pk2 = (u32)ua[j] | ((u32)ub[j] << 16);
        int vd = vd0 + j;
        int off = (vd * 128 + kk * 2) ^ (((vd & 7) ^ ((vd >> 3) & 7)) << 4);
        *(u32*)((char*)Vlds + off) = pk2;
      }
    }
    {
      int row = t >> 3, c8 = t & 7;
      const int* ap = adj + (size_t)(qbase + row) * NN + k0 + c8 * 8;
      int4v a0 = *(const int4v*)ap;
      int4v a1 = *(const int4v*)(ap + 4);
      u32 byteval = (u32)(a0.x > 0)        | ((u32)(a0.y > 0) << 1) |
                    ((u32)(a0.z > 0) << 2) | ((u32)(a0.w > 0) << 3) |
                    ((u32)(a1.x > 0) << 4) | ((u32)(a1.y > 0) << 5) |
                    ((u32)(a1.z > 0) << 6) | ((u32)(a1.w > 0) << 7);
      ((unsigned char*)Abits)[row * 8 + c8] = (unsigned char)byteval;
    }
    __syncthreads();

    f32x4 st[4] = {zero, zero, zero, zero};
    #pragma unroll
    for (int tk = 0; tk < 4; tk++) {
      #pragma unroll
      for (int dc = 0; dc < 2; dc++) {
        int krow = tk * 16 + qi;
        int c = hh * 64 + dc * 32 + g * 8;
        int off = (krow * 256 + c * 2) ^ ((krow & 7) << 4);
        short8 af = *(const short8*)((char*)Klds + off);
        st[tk] = __builtin_amdgcn_mfma_f32_16x16x32_bf16(af, qfrag[dc], st[tk], 0, 0, 0);
      }
    }

    u64 bbm = Abits[q_local];
    u32 blo = (u32)bbm, bhi = (u32)(bbm >> 32);

    float tmax = -1e30f;
    #pragma unroll
    for (int tk = 0; tk < 4; tk++) {
      u32 half = (tk < 2) ? blo : bhi;
      int bb0 = (tk & 1) * 16 + g * 4;
      #pragma unroll
      for (int r = 0; r < 4; r++) {
        float s = st[tk][r];
        s = ((half >> (bb0 + r)) & 1u) ? s : -9e15f;
        st[tk][r] = s;
        tmax = fmaxf(tmax, s);
      }
    }
    tmax = fmaxf(tmax, __shfl_xor(tmax, 16));
    tmax = fmaxf(tmax, __shfl_xor(tmax, 32));
    float newm = fmaxf(mrun, tmax);
    float alpha = __builtin_amdgcn_exp2f(mrun - newm);
    mrun = newm;

    float psum = 0.f;
    u32 pk[8];
    #pragma unroll
    for (int tk = 0; tk < 4; tk++) {
      float p0 = __builtin_amdgcn_exp2f(st[tk][0] - newm);
      float p1 = __builtin_amdgcn_exp2f(st[tk][1] - newm);
      float p2 = __builtin_amdgcn_exp2f(st[tk][2] - newm);
      float p3 = __builtin_amdgcn_exp2f(st[tk][3] - newm);
      psum += (p0 + p1) + (p2 + p3);
      pk[tk * 2 + 0] = (u32)f2bf(p0) | ((u32)f2bf(p1) << 16);
      pk[tk * 2 + 1] = (u32)f2bf(p2) | ((u32)f2bf(p3) << 16);
    }
    psum += __shfl_xor(psum, 16);
    psum += __shfl_xor(psum, 32);
    lsum = lsum * alpha + psum;
    #pragma unroll
    for (int tv = 0; tv < 4; tv++) {
      Ot[tv][0] *= alpha; Ot[tv][1] *= alpha; Ot[tv][2] *= alpha; Ot[tv][3] *= alpha;
    }

    const int srcbase = qi + ((g & 1) << 5);
    #pragma unroll
    for (int kc = 0; kc < 2; kc++) {
      U4 pf;
      #pragma unroll
      for (int jp = 0; jp < 4; jp++) {
        int src = srcbase + ((jp >> 1) << 4);
        u32 va1 = (u32)__shfl((int)pk[4 * kc + (jp & 1)], src);
        u32 vb1 = (u32)__shfl((int)pk[4 * kc + 2 + (jp & 1)], src);
        pf.u[jp] = (g < 2) ? va1 : vb1;
      }
      #pragma unroll
      for (int tv = 0; tv < 4; tv++) {
        int vd = hh * 64 + tv * 16 + qi;
        int off = (vd * 128 + (kc * 32 + g * 8) * 2) ^ (((vd & 7) ^ ((vd >> 3) & 7)) << 4);
        short8 vfrag = *(const short8*)((char*)Vlds + off);
        Ot[tv] = __builtin_amdgcn_mfma_f32_16x16x32_bf16(vfrag, pf.s, Ot[tv], 0, 0, 0);
      }
    }
  }

  float inv = 1.0f / lsum;
  #pragma unroll
  for (int tv = 0; tv < 4; tv++) {
    float4v o;
    o.x = Ot[tv][0] * inv; o.y = Ot[tv][1] * inv;
    o.z = Ot[tv][2] * inv; o.w = Ot[tv][3] * inv;
    *(float4v*)(out + (size_t)qrow * QKD + h * DD + tv * 16 + g * 4) = o;
  }
}

extern "C" void kernel_launch(void* const* d_in, const int* in_sizes, int n_in,
                              void* d_out, int out_size, void* d_ws, size_t ws_size,
                              hipStream_t stream) {
  const float* x1 = (const float*)d_in[0];
  const float* x2 = (const float*)d_in[1];
  const float* v  = (const float*)d_in[2];
  const int* adj  = (const int*)d_in[3];
  float* out = (float*)d_out;

  const size_t szK = (size_t)512 * 4096 * sizeof(u16);     // 4 MB (512 tiles x 8KB)
  const size_t szV = szK;                                   // 4 MB
  const size_t szA = (size_t)NN * 64 * sizeof(u64);         // 2 MB
  const size_t need = szK + szV + szA;

  if (ws_size >= need && d_ws != nullptr) {
    u16* Kbt = (u16*)d_ws;
    u16* Vbt = (u16*)((char*)d_ws + szK);
    u64* Abg = (u64*)((char*)d_ws + szK + szV);
    prepass_fused<<<dim3(5120), dim3(256), 0, stream>>>(x2, v, adj, Kbt, Vbt, Abg);
    attn_fast<<<dim3(512), dim3(256), 0, stream>>>(x1, Abg, Kbt, Vbt, out);
  } else {
    attn_fallback<<<dim3(256), dim3(512), 0, stream>>>(x1, x2, v, adj, out);
  }
}

// Round 7
// 192.811 us; speedup vs baseline: 1.5483x; 1.0864x over previous
//
#include <hip/hip_runtime.h>

#define NN 4096
#define HEADS 8
#define DD 64
#define QKD 512

typedef __attribute__((ext_vector_type(8))) short short8;
typedef __attribute__((ext_vector_type(4))) float f32x4;
typedef __attribute__((ext_vector_type(4))) float float4v;
typedef __attribute__((ext_vector_type(4))) int int4v;
typedef unsigned int u32;
typedef unsigned short u16;
typedef unsigned long long u64;

union U8 { u16 u[8]; short8 s; };
union U4 { u32 u[4]; short8 s; };

__device__ __forceinline__ u16 f2bf(float f) {
  u32 u = __float_as_uint(f);
  u += 0x7fffu + ((u >> 16) & 1u);   // RNE
  return (u16)(u >> 16);
}

__device__ __forceinline__ u32 cvtpk(float lo, float hi) {   // bf16(lo) | bf16(hi)<<16, RNE
  u32 d;
  asm("v_cvt_pk_bf16_f32 %0, %1, %2" : "=v"(d) : "v"(lo), "v"(hi));
  return d;
}

#define GLL(src, dst) __builtin_amdgcn_global_load_lds( \
    (const __attribute__((address_space(1))) void*)(src), \
    (__attribute__((address_space(3))) void*)(dst), 16, 0, 0)

// ============================================================================
// Fused prepass [R6 verbatim] (single launch, 5120 blocks x 256):
//   b in [0,4096):      adj row b -> bitmask Abg[b*64 + m] (u64, bit c = col m*64+c)
//   b in [4096,4608):   x2 -> K bf16 tile images (pre-swizzled)
//   b in [4608,5120):   v  -> V^T bf16 tile images (pre-swizzled)
// K tile (h,kb), 8 KB:  I[off] = K[kb*64+kr][h*64+d],  off = kr*128 + (d*2 ^ ((kr&7)<<4))
// V tile (h,kb), 8 KB:  I[off] = V[kb*64+k ][h*64+vd], off = vd*128 + (k*2 ^ ((vd&7)<<4))
// ============================================================================
__global__ __launch_bounds__(256) void prepass_fused(
    const float* __restrict__ x2, const float* __restrict__ v,
    const int* __restrict__ adj,
    u16* __restrict__ Kbt, u16* __restrict__ Vbt, u64* __restrict__ Abg)
{
  __shared__ u16 Vtmp[64][80];
  const int b = blockIdx.x;
  const int t = threadIdx.x;

  if (b < 4096) {                      // ---------------- ADJ pack (1 row/block)
    const int row = b;
    const int* src = adj + (size_t)row * NN;
    int4v a0 = *(const int4v*)(src + t * 16);
    int4v a1 = *(const int4v*)(src + t * 16 + 4);
    int4v a2 = *(const int4v*)(src + t * 16 + 8);
    int4v a3 = *(const int4v*)(src + t * 16 + 12);
    u32 bits =
        (u32)(a0.x > 0)         | ((u32)(a0.y > 0) << 1)  |
        ((u32)(a0.z > 0) << 2)  | ((u32)(a0.w > 0) << 3)  |
        ((u32)(a1.x > 0) << 4)  | ((u32)(a1.y > 0) << 5)  |
        ((u32)(a1.z > 0) << 6)  | ((u32)(a1.w > 0) << 7)  |
        ((u32)(a2.x > 0) << 8)  | ((u32)(a2.y > 0) << 9)  |
        ((u32)(a2.z > 0) << 10) | ((u32)(a2.w > 0) << 11) |
        ((u32)(a3.x > 0) << 12) | ((u32)(a3.y > 0) << 13) |
        ((u32)(a3.z > 0) << 14) | ((u32)(a3.w > 0) << 15);
    unsigned char* AB = (unsigned char*)Vtmp;
    *(u16*)(AB + t * 2) = (u16)bits;
    __syncthreads();
    if (t < 64) {
      u64 m = *(const u64*)(AB + t * 8);
      Abg[(size_t)row * 64 + t] = m;
    }
  } else if (b < 4608) {               // ---------------- K tiles
    const int j = b - 4096;
    const int h = j >> 6, kb = j & 63;
    u16* dst = Kbt + (size_t)j * 4096;
    #pragma unroll
    for (int i = 0; i < 2; i++) {
      int c = t + i * 256;
      int off = c * 16;
      int kr = off >> 7;
      int db = (off & 127) ^ ((kr & 7) << 4);
      int d0 = db >> 1;
      const float* p = x2 + (size_t)(kb * 64 + kr) * QKD + h * DD + d0;
      float4v a0 = *(const float4v*)p;
      float4v a1 = *(const float4v*)(p + 4);
      U8 r;
      r.u[0] = f2bf(a0.x); r.u[1] = f2bf(a0.y); r.u[2] = f2bf(a0.z); r.u[3] = f2bf(a0.w);
      r.u[4] = f2bf(a1.x); r.u[5] = f2bf(a1.y); r.u[6] = f2bf(a1.z); r.u[7] = f2bf(a1.w);
      *(short8*)((char*)dst + off) = r.s;
    }
  } else {                             // ---------------- V tiles (transpose via LDS)
    const int bb = b - 4608;
    const int h = bb >> 6, kb = bb & 63;
    {
      int k = t >> 2, j0 = (t & 3) * 16;
      const float* p = v + (size_t)(kb * 64 + k) * QKD + h * DD + j0;
      float4v a0 = *(const float4v*)p;
      float4v a1 = *(const float4v*)(p + 4);
      float4v a2 = *(const float4v*)(p + 8);
      float4v a3 = *(const float4v*)(p + 12);
      U8 r0, r1;
      r0.u[0] = f2bf(a0.x); r0.u[1] = f2bf(a0.y); r0.u[2] = f2bf(a0.z); r0.u[3] = f2bf(a0.w);
      r0.u[4] = f2bf(a1.x); r0.u[5] = f2bf(a1.y); r0.u[6] = f2bf(a1.z); r0.u[7] = f2bf(a1.w);
      r1.u[0] = f2bf(a2.x); r1.u[1] = f2bf(a2.y); r1.u[2] = f2bf(a2.z); r1.u[3] = f2bf(a2.w);
      r1.u[4] = f2bf(a3.x); r1.u[5] = f2bf(a3.y); r1.u[6] = f2bf(a3.z); r1.u[7] = f2bf(a3.w);
      *(short8*)(&Vtmp[k][j0]) = r0.s;
      *(short8*)(&Vtmp[k][j0 + 8]) = r1.s;
    }
    __syncthreads();
    u16* dst = Vbt + (size_t)bb * 4096;
    #pragma unroll
    for (int i = 0; i < 2; i++) {
      int c = t + i * 256;
      int off = c * 16;
      int vd = off >> 7;
      int kbyte = (off & 127) ^ ((vd & 7) << 4);
      int k0 = kbyte >> 1;
      U8 r;
      #pragma unroll
      for (int jj = 0; jj < 8; jj++) r.u[jj] = Vtmp[k0 + jj][vd];
      *(short8*)((char*)dst + off) = r.s;
    }
  }
}

// ============================================================================
// Main fused kernel: R6 inner body, restructured for occupancy via in-block
// K-parity split. Grid 512 (64 q-tiles x 8 heads), 512 threads = 8 waves:
//   wave w: qh = w&3 (16 q-rows), kpar = w>>2 (even/odd 64-k tiles).
// Parity p computes tiles kb = 2i+p, i=0..31; per-parity double-buffered
// K/V streams (64 KB LDS -> 2 blocks/CU = 16 waves/CU, 2x R6's 8).
// Final in-block merge: M=max(m1,m2), a_j=exp2(m_j-M),
// out = (O1*a1 + O2*a2) / (l1*a1 + l2*a2).
// ============================================================================
__global__ __launch_bounds__(512, 4) void attn_fast(
    const float* __restrict__ x1,
    const u64* __restrict__ Abg,
    const u16* __restrict__ Kbt, const u16* __restrict__ Vbt,
    float* __restrict__ out)
{
  __shared__ u16 KL[2][2][4096];   // [kpar][buf][8KB tile image]
  __shared__ u16 VL[2][2][4096];

  const int b = blockIdx.x;
  const int widx = ((b & 7) << 6) | (b >> 3);   // XCD-chunked swizzle
  const int qt = widx >> 3;
  const int h = widx & 7;
  const int t = threadIdx.x;
  const int w = t >> 6;
  const int lane = t & 63;
  const int g = lane >> 4;
  const int qi = lane & 15;
  const int qh = w & 3;
  const int kpar = w >> 2;
  const int qrow = qt * 64 + qh * 16 + qi;

  const u16* Ktiles = Kbt + (size_t)h * 64 * 4096;
  const u16* Vtiles = Vbt + (size_t)h * 64 * 4096;
  const u64* arow = Abg + (size_t)qrow * 64;

  const float SCL = 0.125f * 1.4426950408889634f;
  short8 qfrag[2];
  #pragma unroll
  for (int dc = 0; dc < 2; dc++) {
    const float* p = x1 + (size_t)qrow * QKD + h * DD + dc * 32 + g * 8;
    float4v a = *(const float4v*)p;
    float4v c = *(const float4v*)(p + 4);
    U8 r;
    r.u[0] = f2bf(a.x * SCL); r.u[1] = f2bf(a.y * SCL);
    r.u[2] = f2bf(a.z * SCL); r.u[3] = f2bf(a.w * SCL);
    r.u[4] = f2bf(c.x * SCL); r.u[5] = f2bf(c.y * SCL);
    r.u[6] = f2bf(c.z * SCL); r.u[7] = f2bf(c.w * SCL);
    qfrag[dc] = r.s;
  }

  const f32x4 zero = {0.f, 0.f, 0.f, 0.f};
  f32x4 Ot[4] = {zero, zero, zero, zero};
  float mrun = -1e30f;
  float lsum = 0.f;

  // prologue: stage super-iter 0 (tiles 0->par0, 1->par1) into buf 0.
  // Each tile image = 8KB = 512 thr x 16B -> one GLL per thread per tile.
  GLL(Ktiles + 0 * 4096 + t * 8, &KL[0][0][t * 8]);
  GLL(Ktiles + 1 * 4096 + t * 8, &KL[1][0][t * 8]);
  GLL(Vtiles + 0 * 4096 + t * 8, &VL[0][0][t * 8]);
  GLL(Vtiles + 1 * 4096 + t * 8, &VL[1][0][t * 8]);
  u64 adjcur = arow[kpar];
  __syncthreads();

  int cur = 0;
  for (int i = 0; i < 32; i++) {
    // ---- issue next super-iter staging (in flight during compute)
    u64 adjnext = 0;
    if (i < 31) {
      const size_t nt = 2 * (size_t)(i + 1);
      GLL(Ktiles + nt * 4096 + t * 8,       &KL[0][cur ^ 1][t * 8]);
      GLL(Ktiles + (nt + 1) * 4096 + t * 8, &KL[1][cur ^ 1][t * 8]);
      GLL(Vtiles + nt * 4096 + t * 8,       &VL[0][cur ^ 1][t * 8]);
      GLL(Vtiles + (nt + 1) * 4096 + t * 8, &VL[1][cur ^ 1][t * 8]);
      adjnext = arow[nt + kpar];
    }

    // ---- S^T = K_tile . Q^T  [R6 body]
    const char* kbase = (const char*)KL[kpar][cur];
    const char* vbase = (const char*)VL[kpar][cur];
    f32x4 st[4] = {zero, zero, zero, zero};
    __builtin_amdgcn_s_setprio(1);
    #pragma unroll
    for (int tk = 0; tk < 4; tk++) {
      int krow = tk * 16 + qi;
      #pragma unroll
      for (int dc = 0; dc < 2; dc++) {
        int off = (krow * 128 + (dc * 32 + g * 8) * 2) ^ ((krow & 7) << 4);
        short8 af = *(const short8*)(kbase + off);
        st[tk] = __builtin_amdgcn_mfma_f32_16x16x32_bf16(af, qfrag[dc], st[tk], 0, 0, 0);
      }
    }
    __builtin_amdgcn_s_setprio(0);

    u32 blo = (u32)adjcur, bhi = (u32)(adjcur >> 32);

    // ---- mask + tree max
    #pragma unroll
    for (int tk = 0; tk < 4; tk++) {
      u32 half = (tk < 2) ? blo : bhi;
      int bb0 = (tk & 1) * 16 + g * 4;
      #pragma unroll
      for (int r = 0; r < 4; r++) {
        float s = st[tk][r];
        st[tk][r] = ((half >> (bb0 + r)) & 1u) ? s : -9e15f;
      }
    }
    float t0 = fmaxf(fmaxf(st[0][0], st[0][1]), fmaxf(st[0][2], st[0][3]));
    float t1 = fmaxf(fmaxf(st[1][0], st[1][1]), fmaxf(st[1][2], st[1][3]));
    float t2 = fmaxf(fmaxf(st[2][0], st[2][1]), fmaxf(st[2][2], st[2][3]));
    float t3 = fmaxf(fmaxf(st[3][0], st[3][1]), fmaxf(st[3][2], st[3][3]));
    float tmax = fmaxf(fmaxf(t0, t1), fmaxf(t2, t3));
    tmax = fmaxf(tmax, __shfl_xor(tmax, 16));
    tmax = fmaxf(tmax, __shfl_xor(tmax, 32));

    // ---- exact defer-max: alpha==1 identity when all rows stable
    if (!__all(tmax <= mrun)) {
      const float newm = fmaxf(mrun, tmax);
      const float alpha = __builtin_amdgcn_exp2f(mrun - newm);
      lsum *= alpha;
      #pragma unroll
      for (int tv = 0; tv < 4; tv++) {
        Ot[tv][0] *= alpha; Ot[tv][1] *= alpha; Ot[tv][2] *= alpha; Ot[tv][3] *= alpha;
      }
      mrun = newm;
    }

    float psum = 0.f;
    u32 pk[8];
    #pragma unroll
    for (int tk = 0; tk < 4; tk++) {
      float p0 = __builtin_amdgcn_exp2f(st[tk][0] - mrun);
      float p1 = __builtin_amdgcn_exp2f(st[tk][1] - mrun);
      float p2 = __builtin_amdgcn_exp2f(st[tk][2] - mrun);
      float p3 = __builtin_amdgcn_exp2f(st[tk][3] - mrun);
      psum += (p0 + p1) + (p2 + p3);
      pk[tk * 2 + 0] = cvtpk(p0, p1);
      pk[tk * 2 + 1] = cvtpk(p2, p3);
    }
    psum += __shfl_xor(psum, 16);
    psum += __shfl_xor(psum, 32);
    lsum += psum;

    // ---- redistribute P to B-frag layout + PV
    const int srcbase = qi + ((g & 1) << 5);
    #pragma unroll
    for (int kc = 0; kc < 2; kc++) {
      U4 pf;
      #pragma unroll
      for (int jp = 0; jp < 4; jp++) {
        int src = srcbase + ((jp >> 1) << 4);
        u32 va1 = (u32)__shfl((int)pk[4 * kc + (jp & 1)], src);
        u32 vb1 = (u32)__shfl((int)pk[4 * kc + 2 + (jp & 1)], src);
        pf.u[jp] = (g < 2) ? va1 : vb1;
      }
      __builtin_amdgcn_s_setprio(1);
      #pragma unroll
      for (int tv = 0; tv < 4; tv++) {
        int vd = tv * 16 + qi;
        int off = (vd * 128 + (kc * 32 + g * 8) * 2) ^ ((vd & 7) << 4);
        short8 vfrag = *(const short8*)(vbase + off);
        Ot[tv] = __builtin_amdgcn_mfma_f32_16x16x32_bf16(vfrag, pf.s, Ot[tv], 0, 0, 0);
      }
      __builtin_amdgcn_s_setprio(0);
    }

    __syncthreads();   // drains in-flight global_load_lds + barrier
    adjcur = adjnext;
    cur ^= 1;
  }

  // ---- merge the two k-parity partials (waves qh/kpar=0 and qh/kpar=1 share q-rows)
  float* mb = (float*)&KL[0][0][0];            // 20 KB scratch over KL
  const int mbase = (qh * 64 + lane) * 20;
  if (kpar == 1) {
    #pragma unroll
    for (int tv = 0; tv < 4; tv++) {
      mb[mbase + tv * 4 + 0] = Ot[tv][0];
      mb[mbase + tv * 4 + 1] = Ot[tv][1];
      mb[mbase + tv * 4 + 2] = Ot[tv][2];
      mb[mbase + tv * 4 + 3] = Ot[tv][3];
    }
    mb[mbase + 16] = mrun;
    mb[mbase + 17] = lsum;
  }
  __syncthreads();
  if (kpar == 0) {
    const float m2 = mb[mbase + 16];
    const float l2 = mb[mbase + 17];
    const float M = fmaxf(mrun, m2);
    const float a1 = __builtin_amdgcn_exp2f(mrun - M);
    const float a2 = __builtin_amdgcn_exp2f(m2 - M);
    const float inv = 1.0f / (lsum * a1 + l2 * a2);
    #pragma unroll
    for (int tv = 0; tv < 4; tv++) {
      float4v o;
      o.x = (Ot[tv][0] * a1 + mb[mbase + tv * 4 + 0] * a2) * inv;
      o.y = (Ot[tv][1] * a1 + mb[mbase + tv * 4 + 1] * a2) * inv;
      o.z = (Ot[tv][2] * a1 + mb[mbase + tv * 4 + 2] * a2) * inv;
      o.w = (Ot[tv][3] * a1 + mb[mbase + tv * 4 + 3] * a2) * inv;
      *(float4v*)(out + (size_t)qrow * QKD + h * DD + tv * 16 + g * 4) = o;
    }
  }
}

// ============================================================================
// Fallback (no workspace): known-good round-1 kernel, f32 inputs in-kernel.
// ============================================================================
__global__ __launch_bounds__(512) void attn_fallback(
    const float* __restrict__ x1, const float* __restrict__ x2f,
    const float* __restrict__ vf, const int* __restrict__ adj,
    float* __restrict__ out)
{
  __shared__ u16 Klds[64 * 128];
  __shared__ u16 Vlds[128 * 64];
  __shared__ u64 Abits[64];

  const int b = blockIdx.x;
  const int qt = (b & 7) | ((b >> 5) << 3);
  const int hg = (b >> 3) & 3;
  const int h0 = hg * 2;
  const int t = threadIdx.x;
  const int w = t >> 6;
  const int lane = t & 63;
  const int qsub = w >> 1;
  const int hh = w & 1;
  const int h = h0 + hh;
  const int g = lane >> 4;
  const int qi = lane & 15;
  const int qbase = qt * 64;
  const int q_local = qsub * 16 + qi;
  const int qrow = qbase + q_local;

  const float SCL = 0.125f * 1.4426950408889634f;
  short8 qfrag[2];
  #pragma unroll
  for (int dc = 0; dc < 2; dc++) {
    const float* p = x1 + (size_t)qrow * QKD + h * DD + dc * 32 + g * 8;
    float4v a = *(const float4v*)p;
    float4v c = *(const float4v*)(p + 4);
    U8 r;
    r.u[0] = f2bf(a.x * SCL); r.u[1] = f2bf(a.y * SCL);
    r.u[2] = f2bf(a.z * SCL); r.u[3] = f2bf(a.w * SCL);
    r.u[4] = f2bf(c.x * SCL); r.u[5] = f2bf(c.y * SCL);
    r.u[6] = f2bf(c.z * SCL); r.u[7] = f2bf(c.w * SCL);
    qfrag[dc] = r.s;
  }

  const f32x4 zero = {0.f, 0.f, 0.f, 0.f};
  f32x4 Ot[4] = {zero, zero, zero, zero};
  float mrun = -1e30f;
  float lsum = 0.f;

  for (int kb = 0; kb < NN / 64; kb++) {
    const int k0 = kb * 64;
    __syncthreads();
    #pragma unroll
    for (int i = 0; i < 2; i++) {
      int s = t + i * 512;
      int row = s >> 4, c0 = (s & 15) * 8;
      int off = (row * 256 + c0 * 2) ^ ((row & 7) << 4);
      const float* p = x2f + (size_t)(k0 + row) * QKD + h0 * DD + c0;
      float4v a = *(const float4v*)p;
      float4v c = *(const float4v*)(p + 4);
      U8 r;
      r.u[0]=f2bf(a.x); r.u[1]=f2bf(a.y); r.u[2]=f2bf(a.z); r.u[3]=f2bf(a.w);
      r.u[4]=f2bf(c.x); r.u[5]=f2bf(c.y); r.u[6]=f2bf(c.z); r.u[7]=f2bf(c.w);
      *(short8*)((char*)Klds + off) = r.s;
    }
    {
      int vdg = t & 15, kp = t >> 4;
      int vd0 = vdg * 8, kk = kp * 2;
      u16 ua[8], ub[8];
      const float* pa = vf + (size_t)(k0 + kk) * QKD + h0 * DD + vd0;
      float4v a0 = *(const float4v*)pa;
      float4v a1 = *(const float4v*)(pa + 4);
      float4v b0 = *(const float4v*)(pa + QKD);
      float4v b1 = *(const float4v*)(pa + QKD + 4);
      ua[0]=f2bf(a0.x); ua[1]=f2bf(a0.y); ua[2]=f2bf(a0.z); ua[3]=f2bf(a0.w);
      ua[4]=f2bf(a1.x); ua[5]=f2bf(a1.y); ua[6]=f2bf(a1.z); ua[7]=f2bf(a1.w);
      ub[0]=f2bf(b0.x); ub[1]=f2bf(b0.y); ub[2]=f2bf(b0.z); ub[3]=f2bf(b0.w);
      ub[4]=f2bf(b1.x); ub[5]=f2bf(b1.y); ub[6]=f2bf(b1.z); ub[7]=f2bf(b1.w);
      #pragma unroll
      for (int j = 0; j < 8; j++) {
        u32 pk2 = (u32)ua[j] | ((u32)ub[j] << 16);
        int vd = vd0 + j;
        int off = (vd * 128 + kk * 2) ^ (((vd & 7) ^ ((vd >> 3) & 7)) << 4);
        *(u32*)((char*)Vlds + off) = pk2;
      }
    }
    {
      int row = t >> 3, c8 = t & 7;
      const int* ap = adj + (size_t)(qbase + row) * NN + k0 + c8 * 8;
      int4v a0 = *(const int4v*)ap;
      int4v a1 = *(const int4v*)(ap + 4);
      u32 byteval = (u32)(a0.x > 0)        | ((u32)(a0.y > 0) << 1) |
                    ((u32)(a0.z > 0) << 2) | ((u32)(a0.w > 0) << 3) |
                    ((u32)(a1.x > 0) << 4) | ((u32)(a1.y > 0) << 5) |
                    ((u32)(a1.z > 0) << 6) | ((u32)(a1.w > 0) << 7);
      ((unsigned char*)Abits)[row * 8 + c8] = (unsigned char)byteval;
    }
    __syncthreads();

    f32x4 st[4] = {zero, zero, zero, zero};
    #pragma unroll
    for (int tk = 0; tk < 4; tk++) {
      #pragma unroll
      for (int dc = 0; dc < 2; dc++) {
        int krow = tk * 16 + qi;
        int c = hh * 64 + dc * 32 + g * 8;
        int off = (krow * 256 + c * 2) ^ ((krow & 7) << 4);
        short8 af = *(const short8*)((char*)Klds + off);
        st[tk] = __builtin_amdgcn_mfma_f32_16x16x32_bf16(af, qfrag[dc], st[tk], 0, 0, 0);
      }
    }

    u64 bbm = Abits[q_local];
    u32 blo = (u32)bbm, bhi = (u32)(bbm >> 32);

    float tmax = -1e30f;
    #pragma unroll
    for (int tk = 0; tk < 4; tk++) {
      u32 half = (tk < 2) ? blo : bhi;
      int bb0 = (tk & 1) * 16 + g * 4;
      #pragma unroll
      for (int r = 0; r < 4; r++) {
        float s = st[tk][r];
        s = ((half >> (bb0 + r)) & 1u) ? s : -9e15f;
        st[tk][r] = s;
        tmax = fmaxf(tmax, s);
      }
    }
    tmax = fmaxf(tmax, __shfl_xor(tmax, 16));
    tmax = fmaxf(tmax, __shfl_xor(tmax, 32));
    float newm = fmaxf(mrun, tmax);
    float alpha = __builtin_amdgcn_exp2f(mrun - newm);
    mrun = newm;

    float psum = 0.f;
    u32 pk[8];
    #pragma unroll
    for (int tk = 0; tk < 4; tk++) {
      float p0 = __builtin_amdgcn_exp2f(st[tk][0] - newm);
      float p1 = __builtin_amdgcn_exp2f(st[tk][1] - newm);
      float p2 = __builtin_amdgcn_exp2f(st[tk][2] - newm);
      float p3 = __builtin_amdgcn_exp2f(st[tk][3] - newm);
      psum += (p0 + p1) + (p2 + p3);
      pk[tk * 2 + 0] = (u32)f2bf(p0) | ((u32)f2bf(p1) << 16);
      pk[tk * 2 + 1] = (u32)f2bf(p2) | ((u32)f2bf(p3) << 16);
    }
    psum += __shfl_xor(psum, 16);
    psum += __shfl_xor(psum, 32);
    lsum = lsum * alpha + psum;
    #pragma unroll
    for (int tv = 0; tv < 4; tv++) {
      Ot[tv][0] *= alpha; Ot[tv][1] *= alpha; Ot[tv][2] *= alpha; Ot[tv][3] *= alpha;
    }

    const int srcbase = qi + ((g & 1) << 5);
    #pragma unroll
    for (int kc = 0; kc < 2; kc++) {
      U4 pf;
      #pragma unroll
      for (int jp = 0; jp < 4; jp++) {
        int src = srcbase + ((jp >> 1) << 4);
        u32 va1 = (u32)__shfl((int)pk[4 * kc + (jp & 1)], src);
        u32 vb1 = (u32)__shfl((int)pk[4 * kc + 2 + (jp & 1)], src);
        pf.u[jp] = (g < 2) ? va1 : vb1;
      }
      #pragma unroll
      for (int tv = 0; tv < 4; tv++) {
        int vd = hh * 64 + tv * 16 + qi;
        int off = (vd * 128 + (kc * 32 + g * 8) * 2) ^ (((vd & 7) ^ ((vd >> 3) & 7)) << 4);
        short8 vfrag = *(const short8*)((char*)Vlds + off);
        Ot[tv] = __builtin_amdgcn_mfma_f32_16x16x32_bf16(vfrag, pf.s, Ot[tv], 0, 0, 0);
      }
    }
  }

  float inv = 1.0f / lsum;
  #pragma unroll
  for (int tv = 0; tv < 4; tv++) {
    float4v o;
    o.x = Ot[tv][0] * inv; o.y = Ot[tv][1] * inv;
    o.z = Ot[tv][2] * inv; o.w = Ot[tv][3] * inv;
    *(float4v*)(out + (size_t)qrow * QKD + h * DD + tv * 16 + g * 4) = o;
  }
}

extern "C" void kernel_launch(void* const* d_in, const int* in_sizes, int n_in,
                              void* d_out, int out_size, void* d_ws, size_t ws_size,
                              hipStream_t stream) {
  const float* x1 = (const float*)d_in[0];
  const float* x2 = (const float*)d_in[1];
  const float* v  = (const float*)d_in[2];
  const int* adj  = (const int*)d_in[3];
  float* out = (float*)d_out;

  const size_t szK = (size_t)512 * 4096 * sizeof(u16);     // 4 MB (512 tiles x 8KB)
  const size_t szV = szK;                                   // 4 MB
  const size_t szA = (size_t)NN * 64 * sizeof(u64);         // 2 MB
  const size_t need = szK + szV + szA;

  if (ws_size >= need && d_ws != nullptr) {
    u16* Kbt = (u16*)d_ws;
    u16* Vbt = (u16*)((char*)d_ws + szK);
    u64* Abg = (u64*)((char*)d_ws + szK + szV);
    prepass_fused<<<dim3(5120), dim3(256), 0, stream>>>(x2, v, adj, Kbt, Vbt, Abg);
    attn_fast<<<dim3(512), dim3(512), 0, stream>>>(x1, Abg, Kbt, Vbt, out);
  } else {
    attn_fallback<<<dim3(256), dim3(512), 0, stream>>>(x1, x2, v, adj, out);
  }
}